// Round 2
// baseline (657.437 us; speedup 1.0000x reference)
//
#include <hip/hip_runtime.h>
#include <hip/hip_bf16.h>

#define NN 50000
#define NE 800000
#define IN_CH 128
#define HID 32
#define HEADS 8
#define HC 256          // HEADS*HID
#define OUT_CH 64
#define NEG_SLOPE 0.2f

// ---------------- counting sort (CSR by dst) ----------------
// edge_index arrives as int32 (harness passes integers as int).

__global__ void hist_kernel(const int* __restrict__ dst, int* __restrict__ deg) {
    int e = blockIdx.x * blockDim.x + threadIdx.x;
    if (e < NE) atomicAdd(&deg[dst[e]], 1);
}

__global__ void scan_kernel(const int* __restrict__ deg, int* __restrict__ offsets,
                            int* __restrict__ cursor) {
    __shared__ int sums[1024];
    const int t = threadIdx.x;
    const int ITEMS = (NN + 1023) / 1024;           // 49
    int begin = t * ITEMS;
    int end   = begin + ITEMS; if (end > NN) end = NN;
    if (begin > NN) begin = NN;
    int s = 0;
    for (int i = begin; i < end; ++i) s += deg[i];
    sums[t] = s;
    __syncthreads();
    for (int off = 1; off < 1024; off <<= 1) {
        int v = (t >= off) ? sums[t - off] : 0;
        __syncthreads();
        sums[t] += v;
        __syncthreads();
    }
    int prefix = (t == 0) ? 0 : sums[t - 1];
    for (int i = begin; i < end; ++i) {
        offsets[i] = prefix;
        cursor[i]  = prefix;
        prefix += deg[i];
    }
    if (t == 1023) offsets[NN] = sums[1023];
}

__global__ void scatter_kernel(const int* __restrict__ src,
                               const int* __restrict__ dst,
                               int* __restrict__ cursor, int* __restrict__ ssrc) {
    int e = blockIdx.x * blockDim.x + threadIdx.x;
    if (e < NE) {
        int d = dst[e];
        int pos = atomicAdd(&cursor[d], 1);
        ssrc[pos] = src[e];
    }
}

// ---------------- f32 register-tiled GEMM ----------------
// C[M,N] = A[M,K] * B[K,N], row-major. BM=BN=64, BK=16, 256 threads, 4x4 per thread.
__global__ __launch_bounds__(256)
void gemm_f32(const float* __restrict__ A, const float* __restrict__ B,
              float* __restrict__ C, int M, int N, int K) {
    __shared__ float As[16][64 + 4];
    __shared__ float Bs[16][64];
    const int tid = threadIdx.x;
    const int bm = blockIdx.x * 64;
    const int bn = blockIdx.y * 64;
    const int tx = tid % 16;          // n
    const int ty = tid / 16;          // m
    const int arow = tid / 4;         // 0..63
    const int acol = (tid % 4) * 4;   // 0,4,8,12
    const int brow = tid / 16;        // 0..15
    const int bcol = (tid % 16) * 4;  // 0..60

    float acc[4][4] = {};
    for (int k0 = 0; k0 < K; k0 += 16) {
        float4 av = make_float4(0.f, 0.f, 0.f, 0.f);
        int ar = bm + arow;
        if (ar < M) av = *(const float4*)(A + (long)ar * K + k0 + acol);
        As[acol + 0][arow] = av.x;
        As[acol + 1][arow] = av.y;
        As[acol + 2][arow] = av.z;
        As[acol + 3][arow] = av.w;
        float4 bv = *(const float4*)(B + (long)(k0 + brow) * N + bn + bcol);
        *(float4*)&Bs[brow][bcol] = bv;
        __syncthreads();
#pragma unroll
        for (int kk = 0; kk < 16; ++kk) {
            float a[4], b[4];
#pragma unroll
            for (int i = 0; i < 4; ++i) a[i] = As[kk][ty * 4 + i];
#pragma unroll
            for (int j = 0; j < 4; ++j) b[j] = Bs[kk][tx * 4 + j];
#pragma unroll
            for (int i = 0; i < 4; ++i)
#pragma unroll
                for (int j = 0; j < 4; ++j) acc[i][j] += a[i] * b[j];
        }
        __syncthreads();
    }
#pragma unroll
    for (int i = 0; i < 4; ++i) {
        int r = bm + ty * 4 + i;
        if (r < M) {
            float4 v = make_float4(acc[i][0], acc[i][1], acc[i][2], acc[i][3]);
            *(float4*)(C + (long)r * N + bn + tx * 4) = v;
        }
    }
}

// ---------------- attention coefficients ----------------

// layer 1: one thread per (n,h); xs1[n][h*32..] dot att_src1[h][:], att_dst1[h][:]
__global__ void attcoef1(const float* __restrict__ xs, const float* __restrict__ att_s,
                         const float* __restrict__ att_d,
                         float* __restrict__ a_s, float* __restrict__ a_d) {
    int idx = blockIdx.x * blockDim.x + threadIdx.x;   // n*8 + h
    if (idx >= NN * HEADS) return;
    int h = idx & 7;
    const float4* xp = (const float4*)(xs + (long)idx * 32);
    const float4* sp = (const float4*)(att_s + h * 32);
    const float4* dp = (const float4*)(att_d + h * 32);
    float as = 0.f, ad = 0.f;
#pragma unroll
    for (int i = 0; i < 8; ++i) {
        float4 v = xp[i], s = sp[i], d = dp[i];
        as += v.x * s.x + v.y * s.y + v.z * s.z + v.w * s.w;
        ad += v.x * d.x + v.y * d.y + v.z * d.z + v.w * d.w;
    }
    a_s[idx] = as;
    a_d[idx] = ad;
}

// layer 2: one thread per n; xs2[n][0..63] dot att_src2 / att_dst2
__global__ void attcoef2(const float* __restrict__ xs, const float* __restrict__ att_s,
                         const float* __restrict__ att_d,
                         float* __restrict__ a_s, float* __restrict__ a_d) {
    int n = blockIdx.x * blockDim.x + threadIdx.x;
    if (n >= NN) return;
    const float4* xp = (const float4*)(xs + (long)n * 64);
    float as = 0.f, ad = 0.f;
#pragma unroll
    for (int i = 0; i < 16; ++i) {
        float4 v = xp[i];
        float4 s = ((const float4*)att_s)[i];
        float4 d = ((const float4*)att_d)[i];
        as += v.x * s.x + v.y * s.y + v.z * s.z + v.w * s.w;
        ad += v.x * d.x + v.y * d.y + v.z * d.z + v.w * d.w;
    }
    a_s[n] = as;
    a_d[n] = ad;
}

// ---------------- aggregation (gather, CSR) ----------------

__device__ __forceinline__ float lrelu(float x) { return x > 0.f ? x : NEG_SLOPE * x; }

// layer 1: one wave per node; lane l -> head h=l>>3, channels (l&7)*4 .. +3
__global__ __launch_bounds__(256)
void agg1(const float* __restrict__ xs, const float* __restrict__ a_s,
          const float* __restrict__ a_d, const int* __restrict__ offsets,
          const int* __restrict__ ssrc, const float* __restrict__ bias,
          float* __restrict__ out) {
    int wave = (blockIdx.x * blockDim.x + threadIdx.x) >> 6;
    int lane = threadIdx.x & 63;
    if (wave >= NN) return;
    const int n = wave;
    const int h = lane >> 3;
    const int ch = h * 32 + (lane & 7) * 4;

    const float adn = a_d[n * 8 + h];
    float aself = lrelu(a_s[n * 8 + h] + adn);
    const int beg = offsets[n], end = offsets[n + 1];

    // pass 1: max
    float m = aself;
    for (int e = beg; e < end; ++e) {
        int s = ssrc[e];
        m = fmaxf(m, lrelu(a_s[s * 8 + h] + adn));
    }
    // pass 2: denom + weighted sum (self loop first)
    float den = expf(aself - m);
    float4 acc;
    {
        float4 v = *(const float4*)(xs + (long)n * HC + ch);
        acc.x = den * v.x; acc.y = den * v.y; acc.z = den * v.z; acc.w = den * v.w;
    }
    for (int e = beg; e < end; ++e) {
        int s = ssrc[e];
        float p = expf(lrelu(a_s[s * 8 + h] + adn) - m);
        den += p;
        float4 v = *(const float4*)(xs + (long)s * HC + ch);
        acc.x += p * v.x; acc.y += p * v.y; acc.z += p * v.z; acc.w += p * v.w;
    }
    float inv = 1.0f / den;
    float4 b = *(const float4*)(bias + ch);
    float4 o;
    o.x = acc.x * inv + b.x; o.y = acc.y * inv + b.y;
    o.z = acc.z * inv + b.z; o.w = acc.w * inv + b.w;
    // ELU
    o.x = o.x > 0.f ? o.x : expm1f(o.x);
    o.y = o.y > 0.f ? o.y : expm1f(o.y);
    o.z = o.z > 0.f ? o.z : expm1f(o.z);
    o.w = o.w > 0.f ? o.w : expm1f(o.w);
    *(float4*)(out + (long)n * HC + ch) = o;
}

// layer 2: one wave per node; lane l -> channel l (H=1, C=64)
__global__ __launch_bounds__(256)
void agg2(const float* __restrict__ xs, const float* __restrict__ a_s,
          const float* __restrict__ a_d, const int* __restrict__ offsets,
          const int* __restrict__ ssrc, const float* __restrict__ bias,
          float* __restrict__ out) {
    int wave = (blockIdx.x * blockDim.x + threadIdx.x) >> 6;
    int lane = threadIdx.x & 63;
    if (wave >= NN) return;
    const int n = wave;

    const float adn = a_d[n];
    float aself = lrelu(a_s[n] + adn);
    const int beg = offsets[n], end = offsets[n + 1];

    float m = aself;
    for (int e = beg; e < end; ++e) {
        int s = ssrc[e];
        m = fmaxf(m, lrelu(a_s[s] + adn));
    }
    float den = expf(aself - m);
    float acc = den * xs[(long)n * OUT_CH + lane];
    for (int e = beg; e < end; ++e) {
        int s = ssrc[e];
        float p = expf(lrelu(a_s[s] + adn) - m);
        den += p;
        acc += p * xs[(long)s * OUT_CH + lane];
    }
    out[(long)n * OUT_CH + lane] = acc / den + bias[lane];
}

// ---------------- launch ----------------

extern "C" void kernel_launch(void* const* d_in, const int* in_sizes, int n_in,
                              void* d_out, int out_size, void* d_ws, size_t ws_size,
                              hipStream_t stream) {
    const float* x     = (const float*)d_in[0];
    const int*   ei    = (const int*)d_in[1];      // int32 edge index [2, E]
    const float* W1    = (const float*)d_in[2];
    const float* atts1 = (const float*)d_in[3];
    const float* attd1 = (const float*)d_in[4];
    const float* bias1 = (const float*)d_in[5];
    const float* W2    = (const float*)d_in[6];
    const float* atts2 = (const float*)d_in[7];
    const float* attd2 = (const float*)d_in[8];
    const float* bias2 = (const float*)d_in[9];
    float*       out   = (float*)d_out;

    const int* srcp = ei;
    const int* dstp = ei + NE;

    char* ws = (char*)d_ws;
    size_t off = 0;
    auto alloc = [&](size_t bytes) -> void* {
        void* p = ws + off;
        off += (bytes + 255) & ~(size_t)255;
        return p;
    };
    float* xs1     = (float*)alloc((size_t)NN * HC * 4);     // 51.2 MB
    float* h1      = (float*)alloc((size_t)NN * HC * 4);     // 51.2 MB
    float* as1     = (float*)alloc((size_t)NN * HEADS * 4);  // 1.6 MB
    float* ad1     = (float*)alloc((size_t)NN * HEADS * 4);  // 1.6 MB
    int*   deg     = (int*)alloc((size_t)NN * 4);
    int*   offsets = (int*)alloc((size_t)(NN + 1) * 4);
    int*   cursor  = (int*)alloc((size_t)NN * 4);
    int*   ssrc    = (int*)alloc((size_t)NE * 4);            // 3.2 MB
    // layer-2 scratch aliases layer-1 buffers that are dead after agg1:
    float* xs2 = xs1;            // [NN, 64] <= [NN, 256] space
    float* as2 = as1;
    float* ad2 = ad1;

    // --- CSR build (counting sort by dst) ---
    hipMemsetAsync(deg, 0, (size_t)NN * 4, stream);
    hist_kernel<<<(NE + 255) / 256, 256, 0, stream>>>(dstp, deg);
    scan_kernel<<<1, 1024, 0, stream>>>(deg, offsets, cursor);
    scatter_kernel<<<(NE + 255) / 256, 256, 0, stream>>>(srcp, dstp, cursor, ssrc);

    // --- layer 1 ---
    {
        dim3 grid((NN + 63) / 64, HC / 64);
        gemm_f32<<<grid, 256, 0, stream>>>(x, W1, xs1, NN, HC, IN_CH);
    }
    attcoef1<<<(NN * HEADS + 255) / 256, 256, 0, stream>>>(xs1, atts1, attd1, as1, ad1);
    agg1<<<(NN + 3) / 4, 256, 0, stream>>>(xs1, as1, ad1, offsets, ssrc, bias1, h1);

    // --- layer 2 ---
    {
        dim3 grid((NN + 63) / 64, OUT_CH / 64);
        gemm_f32<<<grid, 256, 0, stream>>>(h1, W2, xs2, NN, OUT_CH, HC);
    }
    attcoef2<<<(NN + 255) / 256, 256, 0, stream>>>(xs2, atts2, attd2, as2, ad2);
    agg2<<<(NN + 3) / 4, 256, 0, stream>>>(xs2, as2, ad2, offsets, ssrc, bias2, out);
}

// Round 3
// 582.428 us; speedup vs baseline: 1.1288x; 1.1288x over previous
//
#include <hip/hip_runtime.h>
#include <hip/hip_bf16.h>

#define NN 50000
#define NE 800000
#define IN_CH 128
#define HID 32
#define HEADS 8
#define HC 256          // HEADS*HID
#define OUT_CH 64
#define NEG_SLOPE 0.2f

// ---------------- counting sort (CSR by dst) ----------------

__global__ void hist_kernel(const int* __restrict__ dst, int* __restrict__ deg) {
    int e = blockIdx.x * blockDim.x + threadIdx.x;
    if (e < NE) atomicAdd(&deg[dst[e]], 1);
}

__global__ void scan_kernel(const int* __restrict__ deg, int* __restrict__ offsets,
                            int* __restrict__ cursor) {
    __shared__ int sums[1024];
    const int t = threadIdx.x;
    const int ITEMS = (NN + 1023) / 1024;           // 49
    int begin = t * ITEMS;
    int end   = begin + ITEMS; if (end > NN) end = NN;
    if (begin > NN) begin = NN;
    int s = 0;
    for (int i = begin; i < end; ++i) s += deg[i];
    sums[t] = s;
    __syncthreads();
    for (int off = 1; off < 1024; off <<= 1) {
        int v = (t >= off) ? sums[t - off] : 0;
        __syncthreads();
        sums[t] += v;
        __syncthreads();
    }
    int prefix = (t == 0) ? 0 : sums[t - 1];
    for (int i = begin; i < end; ++i) {
        offsets[i] = prefix;
        cursor[i]  = prefix;
        prefix += deg[i];
    }
    if (t == 1023) offsets[NN] = sums[1023];
}

__global__ void scatter_kernel(const int* __restrict__ src,
                               const int* __restrict__ dst,
                               int* __restrict__ cursor, int* __restrict__ ssrc) {
    int e = blockIdx.x * blockDim.x + threadIdx.x;
    if (e < NE) {
        int d = dst[e];
        int pos = atomicAdd(&cursor[d], 1);
        ssrc[pos] = src[e];
    }
}

// ---------------- f32 GEMM, 128x128 tile (layer 1) ----------------
// C[M,N] = A[M,K]*B[K,N] row-major. 256 threads, each computes a 2x2 grid of
// 4x4 microtiles at offsets {0,64}: rows ty*4+{0..3}(+64), cols tx*4+{0..3}(+64).
// 16B lane stride on LDS reads -> 2-way bank aliasing (free per m136).
__global__ __launch_bounds__(256)
void gemm_f32_128(const float* __restrict__ A, const float* __restrict__ B,
                  float* __restrict__ C, int M, int N, int K) {
    __shared__ float As[16][128 + 4];
    __shared__ float Bs[16][128];
    const int tid = threadIdx.x;
    const int bm = blockIdx.x * 128;
    const int bn = blockIdx.y * 128;
    const int tx = tid & 15;          // col group
    const int ty = tid >> 4;          // row group

    float acc[8][8] = {};
    for (int k0 = 0; k0 < K; k0 += 16) {
        // load A tile: 128x16 floats = 512 float4, 2 per thread
#pragma unroll
        for (int it = 0; it < 2; ++it) {
            int idx = tid + it * 256;
            int r = idx >> 2;               // 0..127
            int c = (idx & 3) * 4;          // 0,4,8,12
            float4 av = make_float4(0.f, 0.f, 0.f, 0.f);
            int ar = bm + r;
            if (ar < M) av = *(const float4*)(A + (long)ar * K + k0 + c);
            As[c + 0][r] = av.x;
            As[c + 1][r] = av.y;
            As[c + 2][r] = av.z;
            As[c + 3][r] = av.w;
        }
        // load B tile: 16x128 floats = 512 float4, 2 per thread
#pragma unroll
        for (int it = 0; it < 2; ++it) {
            int idx = tid + it * 256;
            int r = idx >> 5;               // 0..15
            int c = (idx & 31) * 4;         // 0..124
            *(float4*)&Bs[r][c] = *(const float4*)(B + (long)(k0 + r) * N + bn + c);
        }
        __syncthreads();
#pragma unroll
        for (int kk = 0; kk < 16; ++kk) {
            float a[8], b[8];
            *(float4*)&a[0] = *(const float4*)&As[kk][ty * 4];
            *(float4*)&a[4] = *(const float4*)&As[kk][64 + ty * 4];
            *(float4*)&b[0] = *(const float4*)&Bs[kk][tx * 4];
            *(float4*)&b[4] = *(const float4*)&Bs[kk][64 + tx * 4];
#pragma unroll
            for (int i = 0; i < 8; ++i)
#pragma unroll
                for (int j = 0; j < 8; ++j) acc[i][j] += a[i] * b[j];
        }
        __syncthreads();
    }
#pragma unroll
    for (int ih = 0; ih < 2; ++ih)
#pragma unroll
    for (int i4 = 0; i4 < 4; ++i4) {
        int r = bm + ih * 64 + ty * 4 + i4;
        if (r >= M) continue;
        int i = ih * 4 + i4;
#pragma unroll
        for (int jh = 0; jh < 2; ++jh) {
            float4 v = make_float4(acc[i][jh * 4], acc[i][jh * 4 + 1],
                                   acc[i][jh * 4 + 2], acc[i][jh * 4 + 3]);
            *(float4*)(C + (long)r * N + bn + jh * 64 + tx * 4) = v;
        }
    }
}

// ---------------- f32 GEMM, 64x64 tile (layer 2) ----------------
__global__ __launch_bounds__(256)
void gemm_f32(const float* __restrict__ A, const float* __restrict__ B,
              float* __restrict__ C, int M, int N, int K) {
    __shared__ float As[16][64 + 4];
    __shared__ float Bs[16][64];
    const int tid = threadIdx.x;
    const int bm = blockIdx.x * 64;
    const int bn = blockIdx.y * 64;
    const int tx = tid % 16;
    const int ty = tid / 16;
    const int arow = tid / 4;
    const int acol = (tid % 4) * 4;
    const int brow = tid / 16;
    const int bcol = (tid % 16) * 4;

    float acc[4][4] = {};
    for (int k0 = 0; k0 < K; k0 += 16) {
        float4 av = make_float4(0.f, 0.f, 0.f, 0.f);
        int ar = bm + arow;
        if (ar < M) av = *(const float4*)(A + (long)ar * K + k0 + acol);
        As[acol + 0][arow] = av.x;
        As[acol + 1][arow] = av.y;
        As[acol + 2][arow] = av.z;
        As[acol + 3][arow] = av.w;
        float4 bv = *(const float4*)(B + (long)(k0 + brow) * N + bn + bcol);
        *(float4*)&Bs[brow][bcol] = bv;
        __syncthreads();
#pragma unroll
        for (int kk = 0; kk < 16; ++kk) {
            float a[4], b[4];
#pragma unroll
            for (int i = 0; i < 4; ++i) a[i] = As[kk][ty * 4 + i];
#pragma unroll
            for (int j = 0; j < 4; ++j) b[j] = Bs[kk][tx * 4 + j];
#pragma unroll
            for (int i = 0; i < 4; ++i)
#pragma unroll
                for (int j = 0; j < 4; ++j) acc[i][j] += a[i] * b[j];
        }
        __syncthreads();
    }
#pragma unroll
    for (int i = 0; i < 4; ++i) {
        int r = bm + ty * 4 + i;
        if (r < M) {
            float4 v = make_float4(acc[i][0], acc[i][1], acc[i][2], acc[i][3]);
            *(float4*)(C + (long)r * N + bn + tx * 4) = v;
        }
    }
}

// ---------------- attention coefficients ----------------

__global__ void attcoef1(const float* __restrict__ xs, const float* __restrict__ att_s,
                         const float* __restrict__ att_d,
                         float* __restrict__ a_s, float* __restrict__ a_d) {
    int idx = blockIdx.x * blockDim.x + threadIdx.x;   // n*8 + h
    if (idx >= NN * HEADS) return;
    int h = idx & 7;
    const float4* xp = (const float4*)(xs + (long)idx * 32);
    const float4* sp = (const float4*)(att_s + h * 32);
    const float4* dp = (const float4*)(att_d + h * 32);
    float as = 0.f, ad = 0.f;
#pragma unroll
    for (int i = 0; i < 8; ++i) {
        float4 v = xp[i], s = sp[i], d = dp[i];
        as += v.x * s.x + v.y * s.y + v.z * s.z + v.w * s.w;
        ad += v.x * d.x + v.y * d.y + v.z * d.z + v.w * d.w;
    }
    a_s[idx] = as;
    a_d[idx] = ad;
}

__global__ void attcoef2(const float* __restrict__ xs, const float* __restrict__ att_s,
                         const float* __restrict__ att_d,
                         float* __restrict__ a_s, float* __restrict__ a_d) {
    int n = blockIdx.x * blockDim.x + threadIdx.x;
    if (n >= NN) return;
    const float4* xp = (const float4*)(xs + (long)n * 64);
    float as = 0.f, ad = 0.f;
#pragma unroll
    for (int i = 0; i < 16; ++i) {
        float4 v = xp[i];
        float4 s = ((const float4*)att_s)[i];
        float4 d = ((const float4*)att_d)[i];
        as += v.x * s.x + v.y * s.y + v.z * s.z + v.w * s.w;
        ad += v.x * d.x + v.y * d.y + v.z * d.z + v.w * d.w;
    }
    a_s[n] = as;
    a_d[n] = ad;
}

// ---------------- aggregation (gather, CSR) ----------------

__device__ __forceinline__ float lrelu(float x) { return x > 0.f ? x : NEG_SLOPE * x; }

// layer 1: one wave per node; lane l -> head h=l>>3, channels (l&7)*4..+3.
// Edge loops unrolled x4/x8 so multiple gathers are in flight (MLP).
__global__ __launch_bounds__(256)
void agg1(const float* __restrict__ xs, const float* __restrict__ a_s,
          const float* __restrict__ a_d, const int* __restrict__ offsets,
          const int* __restrict__ ssrc, const float* __restrict__ bias,
          float* __restrict__ out) {
    int wave = (blockIdx.x * blockDim.x + threadIdx.x) >> 6;
    int lane = threadIdx.x & 63;
    if (wave >= NN) return;
    const int n = wave;
    const int h = lane >> 3;
    const int ch = h * 32 + (lane & 7) * 4;

    const float adn = a_d[n * 8 + h];
    float aself = lrelu(a_s[n * 8 + h] + adn);
    const int beg = offsets[n], end = offsets[n + 1];

    // pass 1: max (unroll 8)
    float m = aself;
    int e = beg;
    for (; e + 8 <= end; e += 8) {
        int s[8];
#pragma unroll
        for (int u = 0; u < 8; ++u) s[u] = ssrc[e + u];
        float av[8];
#pragma unroll
        for (int u = 0; u < 8; ++u) av[u] = a_s[s[u] * 8 + h];
#pragma unroll
        for (int u = 0; u < 8; ++u) m = fmaxf(m, lrelu(av[u] + adn));
    }
    for (; e < end; ++e)
        m = fmaxf(m, lrelu(a_s[ssrc[e] * 8 + h] + adn));

    // pass 2: denom + weighted sum (self loop first), unroll 4
    float den = expf(aself - m);
    float4 acc;
    {
        float4 v = *(const float4*)(xs + (long)n * HC + ch);
        acc.x = den * v.x; acc.y = den * v.y; acc.z = den * v.z; acc.w = den * v.w;
    }
    e = beg;
    for (; e + 4 <= end; e += 4) {
        int s0 = ssrc[e], s1 = ssrc[e + 1], s2 = ssrc[e + 2], s3 = ssrc[e + 3];
        float a0 = a_s[s0 * 8 + h], a1 = a_s[s1 * 8 + h];
        float a2 = a_s[s2 * 8 + h], a3 = a_s[s3 * 8 + h];
        float4 v0 = *(const float4*)(xs + (long)s0 * HC + ch);
        float4 v1 = *(const float4*)(xs + (long)s1 * HC + ch);
        float4 v2 = *(const float4*)(xs + (long)s2 * HC + ch);
        float4 v3 = *(const float4*)(xs + (long)s3 * HC + ch);
        float p0 = expf(lrelu(a0 + adn) - m);
        float p1 = expf(lrelu(a1 + adn) - m);
        float p2 = expf(lrelu(a2 + adn) - m);
        float p3 = expf(lrelu(a3 + adn) - m);
        den += (p0 + p1) + (p2 + p3);
        acc.x += p0 * v0.x + p1 * v1.x + p2 * v2.x + p3 * v3.x;
        acc.y += p0 * v0.y + p1 * v1.y + p2 * v2.y + p3 * v3.y;
        acc.z += p0 * v0.z + p1 * v1.z + p2 * v2.z + p3 * v3.z;
        acc.w += p0 * v0.w + p1 * v1.w + p2 * v2.w + p3 * v3.w;
    }
    for (; e < end; ++e) {
        int s = ssrc[e];
        float p = expf(lrelu(a_s[s * 8 + h] + adn) - m);
        den += p;
        float4 v = *(const float4*)(xs + (long)s * HC + ch);
        acc.x += p * v.x; acc.y += p * v.y; acc.z += p * v.z; acc.w += p * v.w;
    }
    float inv = 1.0f / den;
    float4 b = *(const float4*)(bias + ch);
    float4 o;
    o.x = acc.x * inv + b.x; o.y = acc.y * inv + b.y;
    o.z = acc.z * inv + b.z; o.w = acc.w * inv + b.w;
    // ELU
    o.x = o.x > 0.f ? o.x : expm1f(o.x);
    o.y = o.y > 0.f ? o.y : expm1f(o.y);
    o.z = o.z > 0.f ? o.z : expm1f(o.z);
    o.w = o.w > 0.f ? o.w : expm1f(o.w);
    *(float4*)(out + (long)n * HC + ch) = o;
}

// layer 2: one wave per node; lane l -> channel l (H=1, C=64), unroll 4
__global__ __launch_bounds__(256)
void agg2(const float* __restrict__ xs, const float* __restrict__ a_s,
          const float* __restrict__ a_d, const int* __restrict__ offsets,
          const int* __restrict__ ssrc, const float* __restrict__ bias,
          float* __restrict__ out) {
    int wave = (blockIdx.x * blockDim.x + threadIdx.x) >> 6;
    int lane = threadIdx.x & 63;
    if (wave >= NN) return;
    const int n = wave;

    const float adn = a_d[n];
    float aself = lrelu(a_s[n] + adn);
    const int beg = offsets[n], end = offsets[n + 1];

    float m = aself;
    int e = beg;
    for (; e + 8 <= end; e += 8) {
        int s[8];
#pragma unroll
        for (int u = 0; u < 8; ++u) s[u] = ssrc[e + u];
        float av[8];
#pragma unroll
        for (int u = 0; u < 8; ++u) av[u] = a_s[s[u]];
#pragma unroll
        for (int u = 0; u < 8; ++u) m = fmaxf(m, lrelu(av[u] + adn));
    }
    for (; e < end; ++e) m = fmaxf(m, lrelu(a_s[ssrc[e]] + adn));

    float den = expf(aself - m);
    float acc = den * xs[(long)n * OUT_CH + lane];
    e = beg;
    for (; e + 4 <= end; e += 4) {
        int s0 = ssrc[e], s1 = ssrc[e + 1], s2 = ssrc[e + 2], s3 = ssrc[e + 3];
        float a0 = a_s[s0], a1 = a_s[s1], a2 = a_s[s2], a3 = a_s[s3];
        float v0 = xs[(long)s0 * OUT_CH + lane];
        float v1 = xs[(long)s1 * OUT_CH + lane];
        float v2 = xs[(long)s2 * OUT_CH + lane];
        float v3 = xs[(long)s3 * OUT_CH + lane];
        float p0 = expf(lrelu(a0 + adn) - m);
        float p1 = expf(lrelu(a1 + adn) - m);
        float p2 = expf(lrelu(a2 + adn) - m);
        float p3 = expf(lrelu(a3 + adn) - m);
        den += (p0 + p1) + (p2 + p3);
        acc += p0 * v0 + p1 * v1 + p2 * v2 + p3 * v3;
    }
    for (; e < end; ++e) {
        int s = ssrc[e];
        float p = expf(lrelu(a_s[s] + adn) - m);
        den += p;
        acc += p * xs[(long)s * OUT_CH + lane];
    }
    out[(long)n * OUT_CH + lane] = acc / den + bias[lane];
}

// ---------------- launch ----------------

extern "C" void kernel_launch(void* const* d_in, const int* in_sizes, int n_in,
                              void* d_out, int out_size, void* d_ws, size_t ws_size,
                              hipStream_t stream) {
    const float* x     = (const float*)d_in[0];
    const int*   ei    = (const int*)d_in[1];      // int32 edge index [2, E]
    const float* W1    = (const float*)d_in[2];
    const float* atts1 = (const float*)d_in[3];
    const float* attd1 = (const float*)d_in[4];
    const float* bias1 = (const float*)d_in[5];
    const float* W2    = (const float*)d_in[6];
    const float* atts2 = (const float*)d_in[7];
    const float* attd2 = (const float*)d_in[8];
    const float* bias2 = (const float*)d_in[9];
    float*       out   = (float*)d_out;

    const int* srcp = ei;
    const int* dstp = ei + NE;

    char* ws = (char*)d_ws;
    size_t off = 0;
    auto alloc = [&](size_t bytes) -> void* {
        void* p = ws + off;
        off += (bytes + 255) & ~(size_t)255;
        return p;
    };
    float* xs1     = (float*)alloc((size_t)NN * HC * 4);     // 51.2 MB
    float* h1      = (float*)alloc((size_t)NN * HC * 4);     // 51.2 MB
    float* as1     = (float*)alloc((size_t)NN * HEADS * 4);  // 1.6 MB
    float* ad1     = (float*)alloc((size_t)NN * HEADS * 4);  // 1.6 MB
    int*   deg     = (int*)alloc((size_t)NN * 4);
    int*   offsets = (int*)alloc((size_t)(NN + 1) * 4);
    int*   cursor  = (int*)alloc((size_t)NN * 4);
    int*   ssrc    = (int*)alloc((size_t)NE * 4);            // 3.2 MB
    // layer-2 scratch aliases layer-1 buffers that are dead after agg1:
    float* xs2 = xs1;
    float* as2 = as1;
    float* ad2 = ad1;

    // --- CSR build (counting sort by dst) ---
    hipMemsetAsync(deg, 0, (size_t)NN * 4, stream);
    hist_kernel<<<(NE + 255) / 256, 256, 0, stream>>>(dstp, deg);
    scan_kernel<<<1, 1024, 0, stream>>>(deg, offsets, cursor);
    scatter_kernel<<<(NE + 255) / 256, 256, 0, stream>>>(srcp, dstp, cursor, ssrc);

    // --- layer 1 ---
    {
        dim3 grid((NN + 127) / 128, HC / 128);
        gemm_f32_128<<<grid, 256, 0, stream>>>(x, W1, xs1, NN, HC, IN_CH);
    }
    attcoef1<<<(NN * HEADS + 255) / 256, 256, 0, stream>>>(xs1, atts1, attd1, as1, ad1);
    agg1<<<(NN + 3) / 4, 256, 0, stream>>>(xs1, as1, ad1, offsets, ssrc, bias1, h1);

    // --- layer 2 ---
    {
        dim3 grid((NN + 63) / 64, OUT_CH / 64);
        gemm_f32<<<grid, 256, 0, stream>>>(h1, W2, xs2, NN, OUT_CH, HC);
    }
    attcoef2<<<(NN + 255) / 256, 256, 0, stream>>>(xs2, atts2, attd2, as2, ad2);
    agg2<<<(NN + 3) / 4, 256, 0, stream>>>(xs2, as2, ad2, offsets, ssrc, bias2, out);
}

// Round 4
// 550.017 us; speedup vs baseline: 1.1953x; 1.0589x over previous
//
#include <hip/hip_runtime.h>
#include <hip/hip_bf16.h>

#define NN 50000
#define NE 800000
#define IN_CH 128
#define HID 32
#define HEADS 8
#define HC 256          // HEADS*HID
#define OUT_CH 64
#define NEG_SLOPE 0.2f

// ---------------- counting sort (CSR by dst) ----------------

__global__ void hist_kernel(const int* __restrict__ dst, int* __restrict__ deg) {
    int e = blockIdx.x * blockDim.x + threadIdx.x;
    if (e < NE) atomicAdd(&deg[dst[e]], 1);
}

__global__ void scan_kernel(const int* __restrict__ deg, int* __restrict__ offsets,
                            int* __restrict__ cursor) {
    __shared__ int sums[1024];
    const int t = threadIdx.x;
    const int ITEMS = (NN + 1023) / 1024;           // 49
    int begin = t * ITEMS;
    int end   = begin + ITEMS; if (end > NN) end = NN;
    if (begin > NN) begin = NN;
    int s = 0;
    for (int i = begin; i < end; ++i) s += deg[i];
    sums[t] = s;
    __syncthreads();
    for (int off = 1; off < 1024; off <<= 1) {
        int v = (t >= off) ? sums[t - off] : 0;
        __syncthreads();
        sums[t] += v;
        __syncthreads();
    }
    int prefix = (t == 0) ? 0 : sums[t - 1];
    for (int i = begin; i < end; ++i) {
        offsets[i] = prefix;
        cursor[i]  = prefix;
        prefix += deg[i];
    }
    if (t == 1023) offsets[NN] = sums[1023];
}

__global__ void scatter_kernel(const int* __restrict__ src,
                               const int* __restrict__ dst,
                               int* __restrict__ cursor, int* __restrict__ ssrc) {
    int e = blockIdx.x * blockDim.x + threadIdx.x;
    if (e < NE) {
        int d = dst[e];
        int pos = atomicAdd(&cursor[d], 1);
        ssrc[pos] = src[e];
    }
}

// ---------------- f32 GEMM, 128x128 tile (layer 1) ----------------
__global__ __launch_bounds__(256)
void gemm_f32_128(const float* __restrict__ A, const float* __restrict__ B,
                  float* __restrict__ C, int M, int N, int K) {
    __shared__ float As[16][128 + 4];
    __shared__ float Bs[16][128];
    const int tid = threadIdx.x;
    const int bm = blockIdx.x * 128;
    const int bn = blockIdx.y * 128;
    const int tx = tid & 15;
    const int ty = tid >> 4;

    float acc[8][8] = {};
    for (int k0 = 0; k0 < K; k0 += 16) {
#pragma unroll
        for (int it = 0; it < 2; ++it) {
            int idx = tid + it * 256;
            int r = idx >> 2;
            int c = (idx & 3) * 4;
            float4 av = make_float4(0.f, 0.f, 0.f, 0.f);
            int ar = bm + r;
            if (ar < M) av = *(const float4*)(A + (long)ar * K + k0 + c);
            As[c + 0][r] = av.x;
            As[c + 1][r] = av.y;
            As[c + 2][r] = av.z;
            As[c + 3][r] = av.w;
        }
#pragma unroll
        for (int it = 0; it < 2; ++it) {
            int idx = tid + it * 256;
            int r = idx >> 5;
            int c = (idx & 31) * 4;
            *(float4*)&Bs[r][c] = *(const float4*)(B + (long)(k0 + r) * N + bn + c);
        }
        __syncthreads();
#pragma unroll
        for (int kk = 0; kk < 16; ++kk) {
            float a[8], b[8];
            *(float4*)&a[0] = *(const float4*)&As[kk][ty * 4];
            *(float4*)&a[4] = *(const float4*)&As[kk][64 + ty * 4];
            *(float4*)&b[0] = *(const float4*)&Bs[kk][tx * 4];
            *(float4*)&b[4] = *(const float4*)&Bs[kk][64 + tx * 4];
#pragma unroll
            for (int i = 0; i < 8; ++i)
#pragma unroll
                for (int j = 0; j < 8; ++j) acc[i][j] += a[i] * b[j];
        }
        __syncthreads();
    }
#pragma unroll
    for (int ih = 0; ih < 2; ++ih)
#pragma unroll
    for (int i4 = 0; i4 < 4; ++i4) {
        int r = bm + ih * 64 + ty * 4 + i4;
        if (r >= M) continue;
        int i = ih * 4 + i4;
#pragma unroll
        for (int jh = 0; jh < 2; ++jh) {
            float4 v = make_float4(acc[i][jh * 4], acc[i][jh * 4 + 1],
                                   acc[i][jh * 4 + 2], acc[i][jh * 4 + 3]);
            *(float4*)(C + (long)r * N + bn + jh * 64 + tx * 4) = v;
        }
    }
}

// ---------------- f32 GEMM, 64x64 tile (layer 2) ----------------
__global__ __launch_bounds__(256)
void gemm_f32(const float* __restrict__ A, const float* __restrict__ B,
              float* __restrict__ C, int M, int N, int K) {
    __shared__ float As[16][64 + 4];
    __shared__ float Bs[16][64];
    const int tid = threadIdx.x;
    const int bm = blockIdx.x * 64;
    const int bn = blockIdx.y * 64;
    const int tx = tid % 16;
    const int ty = tid / 16;
    const int arow = tid / 4;
    const int acol = (tid % 4) * 4;
    const int brow = tid / 16;
    const int bcol = (tid % 16) * 4;

    float acc[4][4] = {};
    for (int k0 = 0; k0 < K; k0 += 16) {
        float4 av = make_float4(0.f, 0.f, 0.f, 0.f);
        int ar = bm + arow;
        if (ar < M) av = *(const float4*)(A + (long)ar * K + k0 + acol);
        As[acol + 0][arow] = av.x;
        As[acol + 1][arow] = av.y;
        As[acol + 2][arow] = av.z;
        As[acol + 3][arow] = av.w;
        float4 bv = *(const float4*)(B + (long)(k0 + brow) * N + bn + bcol);
        *(float4*)&Bs[brow][bcol] = bv;
        __syncthreads();
#pragma unroll
        for (int kk = 0; kk < 16; ++kk) {
            float a[4], b[4];
#pragma unroll
            for (int i = 0; i < 4; ++i) a[i] = As[kk][ty * 4 + i];
#pragma unroll
            for (int j = 0; j < 4; ++j) b[j] = Bs[kk][tx * 4 + j];
#pragma unroll
            for (int i = 0; i < 4; ++i)
#pragma unroll
                for (int j = 0; j < 4; ++j) acc[i][j] += a[i] * b[j];
        }
        __syncthreads();
    }
#pragma unroll
    for (int i = 0; i < 4; ++i) {
        int r = bm + ty * 4 + i;
        if (r < M) {
            float4 v = make_float4(acc[i][0], acc[i][1], acc[i][2], acc[i][3]);
            *(float4*)(C + (long)r * N + bn + tx * 4) = v;
        }
    }
}

// ---------------- attention coefficients ----------------

__global__ void attcoef1(const float* __restrict__ xs, const float* __restrict__ att_s,
                         const float* __restrict__ att_d,
                         float* __restrict__ a_s, float* __restrict__ a_d) {
    int idx = blockIdx.x * blockDim.x + threadIdx.x;   // n*8 + h
    if (idx >= NN * HEADS) return;
    int h = idx & 7;
    const float4* xp = (const float4*)(xs + (long)idx * 32);
    const float4* sp = (const float4*)(att_s + h * 32);
    const float4* dp = (const float4*)(att_d + h * 32);
    float as = 0.f, ad = 0.f;
#pragma unroll
    for (int i = 0; i < 8; ++i) {
        float4 v = xp[i], s = sp[i], d = dp[i];
        as += v.x * s.x + v.y * s.y + v.z * s.z + v.w * s.w;
        ad += v.x * d.x + v.y * d.y + v.z * d.z + v.w * d.w;
    }
    a_s[idx] = as;
    a_d[idx] = ad;
}

__global__ void attcoef2(const float* __restrict__ xs, const float* __restrict__ att_s,
                         const float* __restrict__ att_d,
                         float* __restrict__ a_s, float* __restrict__ a_d) {
    int n = blockIdx.x * blockDim.x + threadIdx.x;
    if (n >= NN) return;
    const float4* xp = (const float4*)(xs + (long)n * 64);
    float as = 0.f, ad = 0.f;
#pragma unroll
    for (int i = 0; i < 16; ++i) {
        float4 v = xp[i];
        float4 s = ((const float4*)att_s)[i];
        float4 d = ((const float4*)att_d)[i];
        as += v.x * s.x + v.y * s.y + v.z * s.z + v.w * s.w;
        ad += v.x * d.x + v.y * d.y + v.z * d.z + v.w * d.w;
    }
    a_s[n] = as;
    a_d[n] = ad;
}

// ---------------- aggregation (gather, CSR, single-pass softmax) ----------------
// No max-subtraction: scores are ~N(0,1.5^2); max over all edges ~7.5 << 88
// (f32 exp overflow), so exp(alpha) directly is safe and mathematically
// identical to the max-subtracted softmax.

__device__ __forceinline__ float lrelu(float x) { return x > 0.f ? x : NEG_SLOPE * x; }

// layer 1: one wave per node; lane l -> head h=l>>3, channels (l&7)*4..+3.
__global__ __launch_bounds__(256)
void agg1(const float* __restrict__ xs, const float* __restrict__ a_s,
          const float* __restrict__ a_d, const int* __restrict__ offsets,
          const int* __restrict__ ssrc, const float* __restrict__ bias,
          float* __restrict__ out) {
    int wave = (blockIdx.x * blockDim.x + threadIdx.x) >> 6;
    int lane = threadIdx.x & 63;
    if (wave >= NN) return;
    const int n = wave;
    const int h = lane >> 3;
    const int ch = h * 32 + (lane & 7) * 4;

    const float adn = a_d[n * 8 + h];
    const int beg = offsets[n], end = offsets[n + 1];

    float pself = __expf(lrelu(a_s[n * 8 + h] + adn));
    float den = pself;
    float4 acc;
    {
        float4 v = *(const float4*)(xs + (long)n * HC + ch);
        acc.x = pself * v.x; acc.y = pself * v.y;
        acc.z = pself * v.z; acc.w = pself * v.w;
    }
    int e = beg;
    for (; e + 4 <= end; e += 4) {
        int s0 = ssrc[e], s1 = ssrc[e + 1], s2 = ssrc[e + 2], s3 = ssrc[e + 3];
        float a0 = a_s[s0 * 8 + h], a1 = a_s[s1 * 8 + h];
        float a2 = a_s[s2 * 8 + h], a3 = a_s[s3 * 8 + h];
        float4 v0 = *(const float4*)(xs + (long)s0 * HC + ch);
        float4 v1 = *(const float4*)(xs + (long)s1 * HC + ch);
        float4 v2 = *(const float4*)(xs + (long)s2 * HC + ch);
        float4 v3 = *(const float4*)(xs + (long)s3 * HC + ch);
        float p0 = __expf(lrelu(a0 + adn));
        float p1 = __expf(lrelu(a1 + adn));
        float p2 = __expf(lrelu(a2 + adn));
        float p3 = __expf(lrelu(a3 + adn));
        den += (p0 + p1) + (p2 + p3);
        acc.x += p0 * v0.x + p1 * v1.x + p2 * v2.x + p3 * v3.x;
        acc.y += p0 * v0.y + p1 * v1.y + p2 * v2.y + p3 * v3.y;
        acc.z += p0 * v0.z + p1 * v1.z + p2 * v2.z + p3 * v3.z;
        acc.w += p0 * v0.w + p1 * v1.w + p2 * v2.w + p3 * v3.w;
    }
    for (; e < end; ++e) {
        int s = ssrc[e];
        float p = __expf(lrelu(a_s[s * 8 + h] + adn));
        den += p;
        float4 v = *(const float4*)(xs + (long)s * HC + ch);
        acc.x += p * v.x; acc.y += p * v.y; acc.z += p * v.z; acc.w += p * v.w;
    }
    float inv = 1.0f / den;
    float4 b = *(const float4*)(bias + ch);
    float4 o;
    o.x = acc.x * inv + b.x; o.y = acc.y * inv + b.y;
    o.z = acc.z * inv + b.z; o.w = acc.w * inv + b.w;
    // ELU
    o.x = o.x > 0.f ? o.x : expm1f(o.x);
    o.y = o.y > 0.f ? o.y : expm1f(o.y);
    o.z = o.z > 0.f ? o.z : expm1f(o.z);
    o.w = o.w > 0.f ? o.w : expm1f(o.w);
    *(float4*)(out + (long)n * HC + ch) = o;
}

// layer 2: one wave per node; lane l -> channel l (H=1, C=64)
__global__ __launch_bounds__(256)
void agg2(const float* __restrict__ xs, const float* __restrict__ a_s,
          const float* __restrict__ a_d, const int* __restrict__ offsets,
          const int* __restrict__ ssrc, const float* __restrict__ bias,
          float* __restrict__ out) {
    int wave = (blockIdx.x * blockDim.x + threadIdx.x) >> 6;
    int lane = threadIdx.x & 63;
    if (wave >= NN) return;
    const int n = wave;

    const float adn = a_d[n];
    const int beg = offsets[n], end = offsets[n + 1];

    float pself = __expf(lrelu(a_s[n] + adn));
    float den = pself;
    float acc = pself * xs[(long)n * OUT_CH + lane];
    int e = beg;
    for (; e + 4 <= end; e += 4) {
        int s0 = ssrc[e], s1 = ssrc[e + 1], s2 = ssrc[e + 2], s3 = ssrc[e + 3];
        float a0 = a_s[s0], a1 = a_s[s1], a2 = a_s[s2], a3 = a_s[s3];
        float v0 = xs[(long)s0 * OUT_CH + lane];
        float v1 = xs[(long)s1 * OUT_CH + lane];
        float v2 = xs[(long)s2 * OUT_CH + lane];
        float v3 = xs[(long)s3 * OUT_CH + lane];
        float p0 = __expf(lrelu(a0 + adn));
        float p1 = __expf(lrelu(a1 + adn));
        float p2 = __expf(lrelu(a2 + adn));
        float p3 = __expf(lrelu(a3 + adn));
        den += (p0 + p1) + (p2 + p3);
        acc += p0 * v0 + p1 * v1 + p2 * v2 + p3 * v3;
    }
    for (; e < end; ++e) {
        int s = ssrc[e];
        float p = __expf(lrelu(a_s[s] + adn));
        den += p;
        acc += p * xs[(long)s * OUT_CH + lane];
    }
    out[(long)n * OUT_CH + lane] = acc / den + bias[lane];
}

// ---------------- launch ----------------

extern "C" void kernel_launch(void* const* d_in, const int* in_sizes, int n_in,
                              void* d_out, int out_size, void* d_ws, size_t ws_size,
                              hipStream_t stream) {
    const float* x     = (const float*)d_in[0];
    const int*   ei    = (const int*)d_in[1];      // int32 edge index [2, E]
    const float* W1    = (const float*)d_in[2];
    const float* atts1 = (const float*)d_in[3];
    const float* attd1 = (const float*)d_in[4];
    const float* bias1 = (const float*)d_in[5];
    const float* W2    = (const float*)d_in[6];
    const float* atts2 = (const float*)d_in[7];
    const float* attd2 = (const float*)d_in[8];
    const float* bias2 = (const float*)d_in[9];
    float*       out   = (float*)d_out;

    const int* srcp = ei;
    const int* dstp = ei + NE;

    char* ws = (char*)d_ws;
    size_t off = 0;
    auto alloc = [&](size_t bytes) -> void* {
        void* p = ws + off;
        off += (bytes + 255) & ~(size_t)255;
        return p;
    };
    float* xs1     = (float*)alloc((size_t)NN * HC * 4);     // 51.2 MB
    float* h1      = (float*)alloc((size_t)NN * HC * 4);     // 51.2 MB
    float* as1     = (float*)alloc((size_t)NN * HEADS * 4);  // 1.6 MB
    float* ad1     = (float*)alloc((size_t)NN * HEADS * 4);  // 1.6 MB
    int*   deg     = (int*)alloc((size_t)NN * 4);
    int*   offsets = (int*)alloc((size_t)(NN + 1) * 4);
    int*   cursor  = (int*)alloc((size_t)NN * 4);
    int*   ssrc    = (int*)alloc((size_t)NE * 4);            // 3.2 MB
    float* xs2 = xs1;
    float* as2 = as1;
    float* ad2 = ad1;

    // --- CSR build (counting sort by dst) ---
    hipMemsetAsync(deg, 0, (size_t)NN * 4, stream);
    hist_kernel<<<(NE + 255) / 256, 256, 0, stream>>>(dstp, deg);
    scan_kernel<<<1, 1024, 0, stream>>>(deg, offsets, cursor);
    scatter_kernel<<<(NE + 255) / 256, 256, 0, stream>>>(srcp, dstp, cursor, ssrc);

    // --- layer 1 ---
    {
        dim3 grid((NN + 127) / 128, HC / 128);
        gemm_f32_128<<<grid, 256, 0, stream>>>(x, W1, xs1, NN, HC, IN_CH);
    }
    attcoef1<<<(NN * HEADS + 255) / 256, 256, 0, stream>>>(xs1, atts1, attd1, as1, ad1);
    agg1<<<(NN + 3) / 4, 256, 0, stream>>>(xs1, as1, ad1, offsets, ssrc, bias1, h1);

    // --- layer 2 ---
    {
        dim3 grid((NN + 63) / 64, OUT_CH / 64);
        gemm_f32<<<grid, 256, 0, stream>>>(h1, W2, xs2, NN, OUT_CH, HC);
    }
    attcoef2<<<(NN + 255) / 256, 256, 0, stream>>>(xs2, atts2, attd2, as2, ad2);
    agg2<<<(NN + 3) / 4, 256, 0, stream>>>(xs2, as2, ad2, offsets, ssrc, bias2, out);
}

// Round 5
// 539.256 us; speedup vs baseline: 1.2192x; 1.0200x over previous
//
#include <hip/hip_runtime.h>
#include <hip/hip_bf16.h>

#define NN 50000
#define NE 800000
#define IN_CH 128
#define HID 32
#define HEADS 8
#define HC 256          // HEADS*HID
#define OUT_CH 64
#define NEG_SLOPE 0.2f

// ---------------- counting sort (CSR by dst) ----------------

__global__ void hist_kernel(const int* __restrict__ dst, int* __restrict__ deg) {
    int e = blockIdx.x * blockDim.x + threadIdx.x;
    if (e < NE) atomicAdd(&deg[dst[e]], 1);
}

__global__ void scan_kernel(const int* __restrict__ deg, int* __restrict__ offsets,
                            int* __restrict__ cursor) {
    __shared__ int sums[1024];
    const int t = threadIdx.x;
    const int ITEMS = (NN + 1023) / 1024;           // 49
    int begin = t * ITEMS;
    int end   = begin + ITEMS; if (end > NN) end = NN;
    if (begin > NN) begin = NN;
    int s = 0;
    for (int i = begin; i < end; ++i) s += deg[i];
    sums[t] = s;
    __syncthreads();
    for (int off = 1; off < 1024; off <<= 1) {
        int v = (t >= off) ? sums[t - off] : 0;
        __syncthreads();
        sums[t] += v;
        __syncthreads();
    }
    int prefix = (t == 0) ? 0 : sums[t - 1];
    for (int i = begin; i < end; ++i) {
        offsets[i] = prefix;
        cursor[i]  = prefix;
        prefix += deg[i];
    }
    if (t == 1023) offsets[NN] = sums[1023];
}

__global__ void scatter_kernel(const int* __restrict__ src,
                               const int* __restrict__ dst,
                               int* __restrict__ cursor, int* __restrict__ ssrc) {
    int e = blockIdx.x * blockDim.x + threadIdx.x;
    if (e < NE) {
        int d = dst[e];
        int pos = atomicAdd(&cursor[d], 1);
        ssrc[pos] = src[e];
    }
}

// ---------------- f32 GEMM, 128x128 tile (layer 1) ----------------
__global__ __launch_bounds__(256)
void gemm_f32_128(const float* __restrict__ A, const float* __restrict__ B,
                  float* __restrict__ C, int M, int N, int K) {
    __shared__ float As[16][128 + 4];
    __shared__ float Bs[16][128];
    const int tid = threadIdx.x;
    const int bm = blockIdx.x * 128;
    const int bn = blockIdx.y * 128;
    const int tx = tid & 15;
    const int ty = tid >> 4;

    float acc[8][8] = {};
    for (int k0 = 0; k0 < K; k0 += 16) {
#pragma unroll
        for (int it = 0; it < 2; ++it) {
            int idx = tid + it * 256;
            int r = idx >> 2;
            int c = (idx & 3) * 4;
            float4 av = make_float4(0.f, 0.f, 0.f, 0.f);
            int ar = bm + r;
            if (ar < M) av = *(const float4*)(A + (long)ar * K + k0 + c);
            As[c + 0][r] = av.x;
            As[c + 1][r] = av.y;
            As[c + 2][r] = av.z;
            As[c + 3][r] = av.w;
        }
#pragma unroll
        for (int it = 0; it < 2; ++it) {
            int idx = tid + it * 256;
            int r = idx >> 5;
            int c = (idx & 31) * 4;
            *(float4*)&Bs[r][c] = *(const float4*)(B + (long)(k0 + r) * N + bn + c);
        }
        __syncthreads();
#pragma unroll
        for (int kk = 0; kk < 16; ++kk) {
            float a[8], b[8];
            *(float4*)&a[0] = *(const float4*)&As[kk][ty * 4];
            *(float4*)&a[4] = *(const float4*)&As[kk][64 + ty * 4];
            *(float4*)&b[0] = *(const float4*)&Bs[kk][tx * 4];
            *(float4*)&b[4] = *(const float4*)&Bs[kk][64 + tx * 4];
#pragma unroll
            for (int i = 0; i < 8; ++i)
#pragma unroll
                for (int j = 0; j < 8; ++j) acc[i][j] += a[i] * b[j];
        }
        __syncthreads();
    }
#pragma unroll
    for (int ih = 0; ih < 2; ++ih)
#pragma unroll
    for (int i4 = 0; i4 < 4; ++i4) {
        int r = bm + ih * 64 + ty * 4 + i4;
        if (r >= M) continue;
        int i = ih * 4 + i4;
#pragma unroll
        for (int jh = 0; jh < 2; ++jh) {
            float4 v = make_float4(acc[i][jh * 4], acc[i][jh * 4 + 1],
                                   acc[i][jh * 4 + 2], acc[i][jh * 4 + 3]);
            *(float4*)(C + (long)r * N + bn + jh * 64 + tx * 4) = v;
        }
    }
}

// ---------------- f32 GEMM, 64x64 tile (layer 2) ----------------
__global__ __launch_bounds__(256)
void gemm_f32(const float* __restrict__ A, const float* __restrict__ B,
              float* __restrict__ C, int M, int N, int K) {
    __shared__ float As[16][64 + 4];
    __shared__ float Bs[16][64];
    const int tid = threadIdx.x;
    const int bm = blockIdx.x * 64;
    const int bn = blockIdx.y * 64;
    const int tx = tid % 16;
    const int ty = tid / 16;
    const int arow = tid / 4;
    const int acol = (tid % 4) * 4;
    const int brow = tid / 16;
    const int bcol = (tid % 16) * 4;

    float acc[4][4] = {};
    for (int k0 = 0; k0 < K; k0 += 16) {
        float4 av = make_float4(0.f, 0.f, 0.f, 0.f);
        int ar = bm + arow;
        if (ar < M) av = *(const float4*)(A + (long)ar * K + k0 + acol);
        As[acol + 0][arow] = av.x;
        As[acol + 1][arow] = av.y;
        As[acol + 2][arow] = av.z;
        As[acol + 3][arow] = av.w;
        float4 bv = *(const float4*)(B + (long)(k0 + brow) * N + bn + bcol);
        *(float4*)&Bs[brow][bcol] = bv;
        __syncthreads();
#pragma unroll
        for (int kk = 0; kk < 16; ++kk) {
            float a[4], b[4];
#pragma unroll
            for (int i = 0; i < 4; ++i) a[i] = As[kk][ty * 4 + i];
#pragma unroll
            for (int j = 0; j < 4; ++j) b[j] = Bs[kk][tx * 4 + j];
#pragma unroll
            for (int i = 0; i < 4; ++i)
#pragma unroll
                for (int j = 0; j < 4; ++j) acc[i][j] += a[i] * b[j];
        }
        __syncthreads();
    }
#pragma unroll
    for (int i = 0; i < 4; ++i) {
        int r = bm + ty * 4 + i;
        if (r < M) {
            float4 v = make_float4(acc[i][0], acc[i][1], acc[i][2], acc[i][3]);
            *(float4*)(C + (long)r * N + bn + tx * 4) = v;
        }
    }
}

// ---------------- attention coefficients ----------------

__global__ void attcoef1(const float* __restrict__ xs, const float* __restrict__ att_s,
                         const float* __restrict__ att_d,
                         float* __restrict__ a_s, float* __restrict__ a_d) {
    int idx = blockIdx.x * blockDim.x + threadIdx.x;   // n*8 + h
    if (idx >= NN * HEADS) return;
    int h = idx & 7;
    const float4* xp = (const float4*)(xs + (long)idx * 32);
    const float4* sp = (const float4*)(att_s + h * 32);
    const float4* dp = (const float4*)(att_d + h * 32);
    float as = 0.f, ad = 0.f;
#pragma unroll
    for (int i = 0; i < 8; ++i) {
        float4 v = xp[i], s = sp[i], d = dp[i];
        as += v.x * s.x + v.y * s.y + v.z * s.z + v.w * s.w;
        ad += v.x * d.x + v.y * d.y + v.z * d.z + v.w * d.w;
    }
    a_s[idx] = as;
    a_d[idx] = ad;
}

__global__ void attcoef2(const float* __restrict__ xs, const float* __restrict__ att_s,
                         const float* __restrict__ att_d,
                         float* __restrict__ a_s, float* __restrict__ a_d) {
    int n = blockIdx.x * blockDim.x + threadIdx.x;
    if (n >= NN) return;
    const float4* xp = (const float4*)(xs + (long)n * 64);
    float as = 0.f, ad = 0.f;
#pragma unroll
    for (int i = 0; i < 16; ++i) {
        float4 v = xp[i];
        float4 s = ((const float4*)att_s)[i];
        float4 d = ((const float4*)att_d)[i];
        as += v.x * s.x + v.y * s.y + v.z * s.z + v.w * s.w;
        ad += v.x * d.x + v.y * d.y + v.z * d.z + v.w * d.w;
    }
    a_s[n] = as;
    a_d[n] = ad;
}

// ---------------- aggregation (gather, CSR, single-pass softmax) ----------------
// Chunked two-phase: (1) one coalesced load grabs 64 edge indices per wave;
// (2) lane u computes edge u's 8 head-scores into LDS (stride 9 -> 2 lanes/bank);
// (3) gather phase has NO dependent global loads: shfl(index) + LDS(score) +
//     streamed 1KB row gathers, unrolled 8/4.
// No max-subtraction: scores ~N(0,1.5^2), max ~7.5 << 88 (f32 exp overflow).

__device__ __forceinline__ float lrelu(float x) { return x > 0.f ? x : NEG_SLOPE * x; }

__global__ __launch_bounds__(256)
void agg1(const float* __restrict__ xs, const float* __restrict__ a_s,
          const float* __restrict__ a_d, const int* __restrict__ offsets,
          const int* __restrict__ ssrc, const float* __restrict__ bias,
          float* __restrict__ out) {
    __shared__ float pl_all[4][64 * 9];
    const int wslot = threadIdx.x >> 6;
    const int wave = (blockIdx.x * blockDim.x + threadIdx.x) >> 6;
    const int lane = threadIdx.x & 63;
    if (wave >= NN) return;
    float* pl = pl_all[wslot];
    const int n = wave;
    const int h = lane >> 3;
    const int ch = h * 32 + (lane & 7) * 4;

    // broadcast dst coefficients for all heads (score phase) + own head (self)
    const float4 D0 = *(const float4*)(a_d + (long)n * 8);
    const float4 D1 = *(const float4*)(a_d + (long)n * 8 + 4);
    const float adn = a_d[n * 8 + h];
    const int beg = offsets[n], end = offsets[n + 1];

    float pself = __expf(lrelu(a_s[n * 8 + h] + adn));
    float den = pself;
    float4 acc;
    {
        float4 v = *(const float4*)(xs + (long)n * HC + ch);
        acc.x = pself * v.x; acc.y = pself * v.y;
        acc.z = pself * v.z; acc.w = pself * v.w;
    }

    for (int base = beg; base < end; base += 64) {
        const int cnt = min(64, end - base);
        int sidx = 0;
        if (lane < cnt) {
            sidx = ssrc[base + lane];
            const float4* ap = (const float4*)(a_s + (long)sidx * 8);
            float4 A0 = ap[0], A1 = ap[1];
            pl[lane * 9 + 0] = __expf(lrelu(A0.x + D0.x));
            pl[lane * 9 + 1] = __expf(lrelu(A0.y + D0.y));
            pl[lane * 9 + 2] = __expf(lrelu(A0.z + D0.z));
            pl[lane * 9 + 3] = __expf(lrelu(A0.w + D0.w));
            pl[lane * 9 + 4] = __expf(lrelu(A1.x + D1.x));
            pl[lane * 9 + 5] = __expf(lrelu(A1.y + D1.y));
            pl[lane * 9 + 6] = __expf(lrelu(A1.z + D1.z));
            pl[lane * 9 + 7] = __expf(lrelu(A1.w + D1.w));
        }
        // order LDS writes (other lanes) before cross-lane reads; wave-internal,
        // so no __syncthreads (divergent waves would deadlock).
        asm volatile("s_waitcnt lgkmcnt(0)" ::: "memory");

        int u = 0;
        for (; u + 8 <= cnt; u += 8) {
            int s0 = __shfl(sidx, u + 0), s1 = __shfl(sidx, u + 1);
            int s2 = __shfl(sidx, u + 2), s3 = __shfl(sidx, u + 3);
            int s4 = __shfl(sidx, u + 4), s5 = __shfl(sidx, u + 5);
            int s6 = __shfl(sidx, u + 6), s7 = __shfl(sidx, u + 7);
            float4 v0 = *(const float4*)(xs + (long)s0 * HC + ch);
            float4 v1 = *(const float4*)(xs + (long)s1 * HC + ch);
            float4 v2 = *(const float4*)(xs + (long)s2 * HC + ch);
            float4 v3 = *(const float4*)(xs + (long)s3 * HC + ch);
            float4 v4 = *(const float4*)(xs + (long)s4 * HC + ch);
            float4 v5 = *(const float4*)(xs + (long)s5 * HC + ch);
            float4 v6 = *(const float4*)(xs + (long)s6 * HC + ch);
            float4 v7 = *(const float4*)(xs + (long)s7 * HC + ch);
            float p0 = pl[(u + 0) * 9 + h], p1 = pl[(u + 1) * 9 + h];
            float p2 = pl[(u + 2) * 9 + h], p3 = pl[(u + 3) * 9 + h];
            float p4 = pl[(u + 4) * 9 + h], p5 = pl[(u + 5) * 9 + h];
            float p6 = pl[(u + 6) * 9 + h], p7 = pl[(u + 7) * 9 + h];
            den += ((p0 + p1) + (p2 + p3)) + ((p4 + p5) + (p6 + p7));
            acc.x += p0 * v0.x + p1 * v1.x + p2 * v2.x + p3 * v3.x
                   + p4 * v4.x + p5 * v5.x + p6 * v6.x + p7 * v7.x;
            acc.y += p0 * v0.y + p1 * v1.y + p2 * v2.y + p3 * v3.y
                   + p4 * v4.y + p5 * v5.y + p6 * v6.y + p7 * v7.y;
            acc.z += p0 * v0.z + p1 * v1.z + p2 * v2.z + p3 * v3.z
                   + p4 * v4.z + p5 * v5.z + p6 * v6.z + p7 * v7.z;
            acc.w += p0 * v0.w + p1 * v1.w + p2 * v2.w + p3 * v3.w
                   + p4 * v4.w + p5 * v5.w + p6 * v6.w + p7 * v7.w;
        }
        for (; u + 4 <= cnt; u += 4) {
            int s0 = __shfl(sidx, u + 0), s1 = __shfl(sidx, u + 1);
            int s2 = __shfl(sidx, u + 2), s3 = __shfl(sidx, u + 3);
            float4 v0 = *(const float4*)(xs + (long)s0 * HC + ch);
            float4 v1 = *(const float4*)(xs + (long)s1 * HC + ch);
            float4 v2 = *(const float4*)(xs + (long)s2 * HC + ch);
            float4 v3 = *(const float4*)(xs + (long)s3 * HC + ch);
            float p0 = pl[(u + 0) * 9 + h], p1 = pl[(u + 1) * 9 + h];
            float p2 = pl[(u + 2) * 9 + h], p3 = pl[(u + 3) * 9 + h];
            den += (p0 + p1) + (p2 + p3);
            acc.x += p0 * v0.x + p1 * v1.x + p2 * v2.x + p3 * v3.x;
            acc.y += p0 * v0.y + p1 * v1.y + p2 * v2.y + p3 * v3.y;
            acc.z += p0 * v0.z + p1 * v1.z + p2 * v2.z + p3 * v3.z;
            acc.w += p0 * v0.w + p1 * v1.w + p2 * v2.w + p3 * v3.w;
        }
        for (; u < cnt; ++u) {
            int s = __shfl(sidx, u);
            float p = pl[u * 9 + h];
            float4 v = *(const float4*)(xs + (long)s * HC + ch);
            den += p;
            acc.x += p * v.x; acc.y += p * v.y; acc.z += p * v.z; acc.w += p * v.w;
        }
    }
    float inv = 1.0f / den;
    float4 b = *(const float4*)(bias + ch);
    float4 o;
    o.x = acc.x * inv + b.x; o.y = acc.y * inv + b.y;
    o.z = acc.z * inv + b.z; o.w = acc.w * inv + b.w;
    // ELU
    o.x = o.x > 0.f ? o.x : expm1f(o.x);
    o.y = o.y > 0.f ? o.y : expm1f(o.y);
    o.z = o.z > 0.f ? o.z : expm1f(o.z);
    o.w = o.w > 0.f ? o.w : expm1f(o.w);
    *(float4*)(out + (long)n * HC + ch) = o;
}

// layer 2: H=1, C=64; scores carried in registers via shfl (no LDS needed).
__global__ __launch_bounds__(256)
void agg2(const float* __restrict__ xs, const float* __restrict__ a_s,
          const float* __restrict__ a_d, const int* __restrict__ offsets,
          const int* __restrict__ ssrc, const float* __restrict__ bias,
          float* __restrict__ out) {
    const int wave = (blockIdx.x * blockDim.x + threadIdx.x) >> 6;
    const int lane = threadIdx.x & 63;
    if (wave >= NN) return;
    const int n = wave;

    const float adn = a_d[n];
    const int beg = offsets[n], end = offsets[n + 1];

    float pself = __expf(lrelu(a_s[n] + adn));
    float den = pself;
    float acc = pself * xs[(long)n * OUT_CH + lane];

    for (int base = beg; base < end; base += 64) {
        const int cnt = min(64, end - base);
        int sidx = 0;
        float pe = 0.f;
        if (lane < cnt) {
            sidx = ssrc[base + lane];
            pe = __expf(lrelu(a_s[sidx] + adn));
        }
        int u = 0;
        for (; u + 8 <= cnt; u += 8) {
            int s0 = __shfl(sidx, u + 0), s1 = __shfl(sidx, u + 1);
            int s2 = __shfl(sidx, u + 2), s3 = __shfl(sidx, u + 3);
            int s4 = __shfl(sidx, u + 4), s5 = __shfl(sidx, u + 5);
            int s6 = __shfl(sidx, u + 6), s7 = __shfl(sidx, u + 7);
            float p0 = __shfl(pe, u + 0), p1 = __shfl(pe, u + 1);
            float p2 = __shfl(pe, u + 2), p3 = __shfl(pe, u + 3);
            float p4 = __shfl(pe, u + 4), p5 = __shfl(pe, u + 5);
            float p6 = __shfl(pe, u + 6), p7 = __shfl(pe, u + 7);
            float v0 = xs[(long)s0 * OUT_CH + lane];
            float v1 = xs[(long)s1 * OUT_CH + lane];
            float v2 = xs[(long)s2 * OUT_CH + lane];
            float v3 = xs[(long)s3 * OUT_CH + lane];
            float v4 = xs[(long)s4 * OUT_CH + lane];
            float v5 = xs[(long)s5 * OUT_CH + lane];
            float v6 = xs[(long)s6 * OUT_CH + lane];
            float v7 = xs[(long)s7 * OUT_CH + lane];
            den += ((p0 + p1) + (p2 + p3)) + ((p4 + p5) + (p6 + p7));
            acc += p0 * v0 + p1 * v1 + p2 * v2 + p3 * v3
                 + p4 * v4 + p5 * v5 + p6 * v6 + p7 * v7;
        }
        for (; u + 4 <= cnt; u += 4) {
            int s0 = __shfl(sidx, u + 0), s1 = __shfl(sidx, u + 1);
            int s2 = __shfl(sidx, u + 2), s3 = __shfl(sidx, u + 3);
            float p0 = __shfl(pe, u + 0), p1 = __shfl(pe, u + 1);
            float p2 = __shfl(pe, u + 2), p3 = __shfl(pe, u + 3);
            float v0 = xs[(long)s0 * OUT_CH + lane];
            float v1 = xs[(long)s1 * OUT_CH + lane];
            float v2 = xs[(long)s2 * OUT_CH + lane];
            float v3 = xs[(long)s3 * OUT_CH + lane];
            den += (p0 + p1) + (p2 + p3);
            acc += p0 * v0 + p1 * v1 + p2 * v2 + p3 * v3;
        }
        for (; u < cnt; ++u) {
            int s = __shfl(sidx, u);
            float p = __shfl(pe, u);
            den += p;
            acc += p * xs[(long)s * OUT_CH + lane];
        }
    }
    out[(long)n * OUT_CH + lane] = acc / den + bias[lane];
}

// ---------------- launch ----------------

extern "C" void kernel_launch(void* const* d_in, const int* in_sizes, int n_in,
                              void* d_out, int out_size, void* d_ws, size_t ws_size,
                              hipStream_t stream) {
    const float* x     = (const float*)d_in[0];
    const int*   ei    = (const int*)d_in[1];      // int32 edge index [2, E]
    const float* W1    = (const float*)d_in[2];
    const float* atts1 = (const float*)d_in[3];
    const float* attd1 = (const float*)d_in[4];
    const float* bias1 = (const float*)d_in[5];
    const float* W2    = (const float*)d_in[6];
    const float* atts2 = (const float*)d_in[7];
    const float* attd2 = (const float*)d_in[8];
    const float* bias2 = (const float*)d_in[9];
    float*       out   = (float*)d_out;

    const int* srcp = ei;
    const int* dstp = ei + NE;

    char* ws = (char*)d_ws;
    size_t off = 0;
    auto alloc = [&](size_t bytes) -> void* {
        void* p = ws + off;
        off += (bytes + 255) & ~(size_t)255;
        return p;
    };
    float* xs1     = (float*)alloc((size_t)NN * HC * 4);     // 51.2 MB
    float* h1      = (float*)alloc((size_t)NN * HC * 4);     // 51.2 MB
    float* as1     = (float*)alloc((size_t)NN * HEADS * 4);  // 1.6 MB
    float* ad1     = (float*)alloc((size_t)NN * HEADS * 4);  // 1.6 MB
    int*   deg     = (int*)alloc((size_t)NN * 4);
    int*   offsets = (int*)alloc((size_t)(NN + 1) * 4);
    int*   cursor  = (int*)alloc((size_t)NN * 4);
    int*   ssrc    = (int*)alloc((size_t)NE * 4);            // 3.2 MB
    float* xs2 = xs1;
    float* as2 = as1;
    float* ad2 = ad1;

    // --- CSR build (counting sort by dst) ---
    hipMemsetAsync(deg, 0, (size_t)NN * 4, stream);
    hist_kernel<<<(NE + 255) / 256, 256, 0, stream>>>(dstp, deg);
    scan_kernel<<<1, 1024, 0, stream>>>(deg, offsets, cursor);
    scatter_kernel<<<(NE + 255) / 256, 256, 0, stream>>>(srcp, dstp, cursor, ssrc);

    // --- layer 1 ---
    {
        dim3 grid((NN + 127) / 128, HC / 128);
        gemm_f32_128<<<grid, 256, 0, stream>>>(x, W1, xs1, NN, HC, IN_CH);
    }
    attcoef1<<<(NN * HEADS + 255) / 256, 256, 0, stream>>>(xs1, atts1, attd1, as1, ad1);
    agg1<<<(NN + 3) / 4, 256, 0, stream>>>(xs1, as1, ad1, offsets, ssrc, bias1, h1);

    // --- layer 2 ---
    {
        dim3 grid((NN + 63) / 64, OUT_CH / 64);
        gemm_f32<<<grid, 256, 0, stream>>>(h1, W2, xs2, NN, OUT_CH, HC);
    }
    attcoef2<<<(NN + 255) / 256, 256, 0, stream>>>(xs2, atts2, attd2, as2, ad2);
    agg2<<<(NN + 3) / 4, 256, 0, stream>>>(xs2, as2, ad2, offsets, ssrc, bias2, out);
}

// Round 6
// 477.151 us; speedup vs baseline: 1.3778x; 1.1302x over previous
//
#include <hip/hip_runtime.h>

#define NN 50000
#define NE 800000
#define IN_CH 128
#define HID 32
#define HEADS 8
#define HC 256          // HEADS*HID
#define OUT_CH 64
#define NEG_SLOPE 0.2f

typedef _Float16 half4 __attribute__((ext_vector_type(4)));
typedef _Float16 half8 __attribute__((ext_vector_type(8)));

// ---------------- counting sort (CSR by dst) ----------------

__global__ void hist_kernel(const int* __restrict__ dst, int* __restrict__ deg) {
    int e = blockIdx.x * blockDim.x + threadIdx.x;
    if (e < NE) atomicAdd(&deg[dst[e]], 1);
}

__global__ void scan_kernel(const int* __restrict__ deg, int* __restrict__ offsets,
                            int* __restrict__ cursor) {
    __shared__ int sums[1024];
    const int t = threadIdx.x;
    const int ITEMS = (NN + 1023) / 1024;           // 49
    int begin = t * ITEMS;
    int end   = begin + ITEMS; if (end > NN) end = NN;
    if (begin > NN) begin = NN;
    int s = 0;
    for (int i = begin; i < end; ++i) s += deg[i];
    sums[t] = s;
    __syncthreads();
    for (int off = 1; off < 1024; off <<= 1) {
        int v = (t >= off) ? sums[t - off] : 0;
        __syncthreads();
        sums[t] += v;
        __syncthreads();
    }
    int prefix = (t == 0) ? 0 : sums[t - 1];
    for (int i = begin; i < end; ++i) {
        offsets[i] = prefix;
        cursor[i]  = prefix;
        prefix += deg[i];
    }
    if (t == 1023) offsets[NN] = sums[1023];
}

__global__ void scatter_kernel(const int* __restrict__ src,
                               const int* __restrict__ dst,
                               int* __restrict__ cursor, int* __restrict__ ssrc) {
    int e = blockIdx.x * blockDim.x + threadIdx.x;
    if (e < NE) {
        int d = dst[e];
        int pos = atomicAdd(&cursor[d], 1);
        ssrc[pos] = src[e];
    }
}

// ---------------- f32 GEMM, 128x128 tile, fp16 output (layer 1) ----------------
__global__ __launch_bounds__(256)
void gemm_f32_128_h(const float* __restrict__ A, const float* __restrict__ B,
                    _Float16* __restrict__ C, int M, int N, int K) {
    __shared__ float As[16][128 + 4];
    __shared__ float Bs[16][128];
    const int tid = threadIdx.x;
    const int bm = blockIdx.x * 128;
    const int bn = blockIdx.y * 128;
    const int tx = tid & 15;
    const int ty = tid >> 4;

    float acc[8][8] = {};
    for (int k0 = 0; k0 < K; k0 += 16) {
#pragma unroll
        for (int it = 0; it < 2; ++it) {
            int idx = tid + it * 256;
            int r = idx >> 2;
            int c = (idx & 3) * 4;
            float4 av = make_float4(0.f, 0.f, 0.f, 0.f);
            int ar = bm + r;
            if (ar < M) av = *(const float4*)(A + (long)ar * K + k0 + c);
            As[c + 0][r] = av.x;
            As[c + 1][r] = av.y;
            As[c + 2][r] = av.z;
            As[c + 3][r] = av.w;
        }
#pragma unroll
        for (int it = 0; it < 2; ++it) {
            int idx = tid + it * 256;
            int r = idx >> 5;
            int c = (idx & 31) * 4;
            *(float4*)&Bs[r][c] = *(const float4*)(B + (long)(k0 + r) * N + bn + c);
        }
        __syncthreads();
#pragma unroll
        for (int kk = 0; kk < 16; ++kk) {
            float a[8], b[8];
            *(float4*)&a[0] = *(const float4*)&As[kk][ty * 4];
            *(float4*)&a[4] = *(const float4*)&As[kk][64 + ty * 4];
            *(float4*)&b[0] = *(const float4*)&Bs[kk][tx * 4];
            *(float4*)&b[4] = *(const float4*)&Bs[kk][64 + tx * 4];
#pragma unroll
            for (int i = 0; i < 8; ++i)
#pragma unroll
                for (int j = 0; j < 8; ++j) acc[i][j] += a[i] * b[j];
        }
        __syncthreads();
    }
#pragma unroll
    for (int ih = 0; ih < 2; ++ih)
#pragma unroll
    for (int i4 = 0; i4 < 4; ++i4) {
        int r = bm + ih * 64 + ty * 4 + i4;
        if (r >= M) continue;
        int i = ih * 4 + i4;
#pragma unroll
        for (int jh = 0; jh < 2; ++jh) {
            half4 hv;
            hv[0] = (_Float16)acc[i][jh * 4 + 0];
            hv[1] = (_Float16)acc[i][jh * 4 + 1];
            hv[2] = (_Float16)acc[i][jh * 4 + 2];
            hv[3] = (_Float16)acc[i][jh * 4 + 3];
            *(half4*)(C + (long)r * N + bn + jh * 64 + tx * 4) = hv;
        }
    }
}

// ---------------- f32 GEMM, 64x64 tile, fp16 output (layer 2) ----------------
__global__ __launch_bounds__(256)
void gemm_f32_h(const float* __restrict__ A, const float* __restrict__ B,
                _Float16* __restrict__ C, int M, int N, int K) {
    __shared__ float As[16][64 + 4];
    __shared__ float Bs[16][64];
    const int tid = threadIdx.x;
    const int bm = blockIdx.x * 64;
    const int bn = blockIdx.y * 64;
    const int tx = tid % 16;
    const int ty = tid / 16;
    const int arow = tid / 4;
    const int acol = (tid % 4) * 4;
    const int brow = tid / 16;
    const int bcol = (tid % 16) * 4;

    float acc[4][4] = {};
    for (int k0 = 0; k0 < K; k0 += 16) {
        float4 av = make_float4(0.f, 0.f, 0.f, 0.f);
        int ar = bm + arow;
        if (ar < M) av = *(const float4*)(A + (long)ar * K + k0 + acol);
        As[acol + 0][arow] = av.x;
        As[acol + 1][arow] = av.y;
        As[acol + 2][arow] = av.z;
        As[acol + 3][arow] = av.w;
        float4 bv = *(const float4*)(B + (long)(k0 + brow) * N + bn + bcol);
        *(float4*)&Bs[brow][bcol] = bv;
        __syncthreads();
#pragma unroll
        for (int kk = 0; kk < 16; ++kk) {
            float a[4], b[4];
#pragma unroll
            for (int i = 0; i < 4; ++i) a[i] = As[kk][ty * 4 + i];
#pragma unroll
            for (int j = 0; j < 4; ++j) b[j] = Bs[kk][tx * 4 + j];
#pragma unroll
            for (int i = 0; i < 4; ++i)
#pragma unroll
                for (int j = 0; j < 4; ++j) acc[i][j] += a[i] * b[j];
        }
        __syncthreads();
    }
#pragma unroll
    for (int i = 0; i < 4; ++i) {
        int r = bm + ty * 4 + i;
        if (r < M) {
            half4 hv;
            hv[0] = (_Float16)acc[i][0];
            hv[1] = (_Float16)acc[i][1];
            hv[2] = (_Float16)acc[i][2];
            hv[3] = (_Float16)acc[i][3];
            *(half4*)(C + (long)r * N + bn + tx * 4) = hv;
        }
    }
}

// ---------------- attention coefficients (fp16 features, f32 math) ----------------

__global__ void attcoef1(const _Float16* __restrict__ xs, const float* __restrict__ att_s,
                         const float* __restrict__ att_d,
                         float* __restrict__ a_s, float* __restrict__ a_d) {
    int idx = blockIdx.x * blockDim.x + threadIdx.x;   // n*8 + h
    if (idx >= NN * HEADS) return;
    int h = idx & 7;
    const _Float16* xp = xs + (long)idx * 32;
    const float* sp = att_s + h * 32;
    const float* dp = att_d + h * 32;
    float as = 0.f, ad = 0.f;
#pragma unroll
    for (int i = 0; i < 4; ++i) {
        half8 v = *(const half8*)(xp + i * 8);
#pragma unroll
        for (int j = 0; j < 8; ++j) {
            float f = (float)v[j];
            as += f * sp[i * 8 + j];
            ad += f * dp[i * 8 + j];
        }
    }
    a_s[idx] = as;
    a_d[idx] = ad;
}

__global__ void attcoef2(const _Float16* __restrict__ xs, const float* __restrict__ att_s,
                         const float* __restrict__ att_d,
                         float* __restrict__ a_s, float* __restrict__ a_d) {
    int n = blockIdx.x * blockDim.x + threadIdx.x;
    if (n >= NN) return;
    const _Float16* xp = xs + (long)n * 64;
    float as = 0.f, ad = 0.f;
#pragma unroll
    for (int i = 0; i < 8; ++i) {
        half8 v = *(const half8*)(xp + i * 8);
#pragma unroll
        for (int j = 0; j < 8; ++j) {
            float f = (float)v[j];
            as += f * att_s[i * 8 + j];
            ad += f * att_d[i * 8 + j];
        }
    }
    a_s[n] = as;
    a_d[n] = ad;
}

// ---------------- aggregation (gather, CSR, single-pass softmax) ----------------
// fp16 feature tables halve the random-gather fill traffic (the measured wall:
// ~3.7 TB/s TCC fill at 440 MB). All math in f32.
// No max-subtraction: scores ~N(0,1.5^2), max ~7.5 << 88 (f32 exp overflow).

__device__ __forceinline__ float lrelu(float x) { return x > 0.f ? x : NEG_SLOPE * x; }

__global__ __launch_bounds__(256)
void agg1(const _Float16* __restrict__ xs, const float* __restrict__ a_s,
          const float* __restrict__ a_d, const int* __restrict__ offsets,
          const int* __restrict__ ssrc, const float* __restrict__ bias,
          float* __restrict__ out) {
    __shared__ float pl_all[4][64 * 9];
    const int wslot = threadIdx.x >> 6;
    const int wave = (blockIdx.x * blockDim.x + threadIdx.x) >> 6;
    const int lane = threadIdx.x & 63;
    if (wave >= NN) return;
    float* pl = pl_all[wslot];
    const int n = wave;
    const int h = lane >> 3;
    const int ch = h * 32 + (lane & 7) * 4;

    const float4 D0 = *(const float4*)(a_d + (long)n * 8);
    const float4 D1 = *(const float4*)(a_d + (long)n * 8 + 4);
    const float adn = a_d[n * 8 + h];
    const int beg = offsets[n], end = offsets[n + 1];

    float pself = __expf(lrelu(a_s[n * 8 + h] + adn));
    float den = pself;
    float ax, ay, az, aw;
    {
        half4 v = *(const half4*)(xs + (long)n * HC + ch);
        ax = pself * (float)v[0]; ay = pself * (float)v[1];
        az = pself * (float)v[2]; aw = pself * (float)v[3];
    }

    for (int base = beg; base < end; base += 64) {
        const int cnt = min(64, end - base);
        int sidx = 0;
        if (lane < cnt) {
            sidx = ssrc[base + lane];
            const float4* ap = (const float4*)(a_s + (long)sidx * 8);
            float4 A0 = ap[0], A1 = ap[1];
            pl[lane * 9 + 0] = __expf(lrelu(A0.x + D0.x));
            pl[lane * 9 + 1] = __expf(lrelu(A0.y + D0.y));
            pl[lane * 9 + 2] = __expf(lrelu(A0.z + D0.z));
            pl[lane * 9 + 3] = __expf(lrelu(A0.w + D0.w));
            pl[lane * 9 + 4] = __expf(lrelu(A1.x + D1.x));
            pl[lane * 9 + 5] = __expf(lrelu(A1.y + D1.y));
            pl[lane * 9 + 6] = __expf(lrelu(A1.z + D1.z));
            pl[lane * 9 + 7] = __expf(lrelu(A1.w + D1.w));
        }
        // order LDS writes before cross-lane reads; wave-internal (no __syncthreads:
        // waves are divergent per node and would deadlock).
        asm volatile("s_waitcnt lgkmcnt(0)" ::: "memory");

        int u = 0;
        for (; u + 8 <= cnt; u += 8) {
            int s0 = __shfl(sidx, u + 0), s1 = __shfl(sidx, u + 1);
            int s2 = __shfl(sidx, u + 2), s3 = __shfl(sidx, u + 3);
            int s4 = __shfl(sidx, u + 4), s5 = __shfl(sidx, u + 5);
            int s6 = __shfl(sidx, u + 6), s7 = __shfl(sidx, u + 7);
            half4 v0 = *(const half4*)(xs + (long)s0 * HC + ch);
            half4 v1 = *(const half4*)(xs + (long)s1 * HC + ch);
            half4 v2 = *(const half4*)(xs + (long)s2 * HC + ch);
            half4 v3 = *(const half4*)(xs + (long)s3 * HC + ch);
            half4 v4 = *(const half4*)(xs + (long)s4 * HC + ch);
            half4 v5 = *(const half4*)(xs + (long)s5 * HC + ch);
            half4 v6 = *(const half4*)(xs + (long)s6 * HC + ch);
            half4 v7 = *(const half4*)(xs + (long)s7 * HC + ch);
            float p0 = pl[(u + 0) * 9 + h], p1 = pl[(u + 1) * 9 + h];
            float p2 = pl[(u + 2) * 9 + h], p3 = pl[(u + 3) * 9 + h];
            float p4 = pl[(u + 4) * 9 + h], p5 = pl[(u + 5) * 9 + h];
            float p6 = pl[(u + 6) * 9 + h], p7 = pl[(u + 7) * 9 + h];
            den += ((p0 + p1) + (p2 + p3)) + ((p4 + p5) + (p6 + p7));
            ax += p0 * (float)v0[0] + p1 * (float)v1[0] + p2 * (float)v2[0] + p3 * (float)v3[0]
                + p4 * (float)v4[0] + p5 * (float)v5[0] + p6 * (float)v6[0] + p7 * (float)v7[0];
            ay += p0 * (float)v0[1] + p1 * (float)v1[1] + p2 * (float)v2[1] + p3 * (float)v3[1]
                + p4 * (float)v4[1] + p5 * (float)v5[1] + p6 * (float)v6[1] + p7 * (float)v7[1];
            az += p0 * (float)v0[2] + p1 * (float)v1[2] + p2 * (float)v2[2] + p3 * (float)v3[2]
                + p4 * (float)v4[2] + p5 * (float)v5[2] + p6 * (float)v6[2] + p7 * (float)v7[2];
            aw += p0 * (float)v0[3] + p1 * (float)v1[3] + p2 * (float)v2[3] + p3 * (float)v3[3]
                + p4 * (float)v4[3] + p5 * (float)v5[3] + p6 * (float)v6[3] + p7 * (float)v7[3];
        }
        for (; u < cnt; ++u) {
            int s = __shfl(sidx, u);
            float p = pl[u * 9 + h];
            half4 v = *(const half4*)(xs + (long)s * HC + ch);
            den += p;
            ax += p * (float)v[0]; ay += p * (float)v[1];
            az += p * (float)v[2]; aw += p * (float)v[3];
        }
    }
    float inv = 1.0f / den;
    float4 b = *(const float4*)(bias + ch);
    float4 o;
    o.x = ax * inv + b.x; o.y = ay * inv + b.y;
    o.z = az * inv + b.z; o.w = aw * inv + b.w;
    // ELU
    o.x = o.x > 0.f ? o.x : expm1f(o.x);
    o.y = o.y > 0.f ? o.y : expm1f(o.y);
    o.z = o.z > 0.f ? o.z : expm1f(o.z);
    o.w = o.w > 0.f ? o.w : expm1f(o.w);
    *(float4*)(out + (long)n * HC + ch) = o;
}

// layer 2: H=1, C=64; scores via shfl; fp16 rows of 128B.
__global__ __launch_bounds__(256)
void agg2(const _Float16* __restrict__ xs, const float* __restrict__ a_s,
          const float* __restrict__ a_d, const int* __restrict__ offsets,
          const int* __restrict__ ssrc, const float* __restrict__ bias,
          float* __restrict__ out) {
    const int wave = (blockIdx.x * blockDim.x + threadIdx.x) >> 6;
    const int lane = threadIdx.x & 63;
    if (wave >= NN) return;
    const int n = wave;

    const float adn = a_d[n];
    const int beg = offsets[n], end = offsets[n + 1];

    float pself = __expf(lrelu(a_s[n] + adn));
    float den = pself;
    float acc = pself * (float)xs[(long)n * OUT_CH + lane];

    for (int base = beg; base < end; base += 64) {
        const int cnt = min(64, end - base);
        int sidx = 0;
        float pe = 0.f;
        if (lane < cnt) {
            sidx = ssrc[base + lane];
            pe = __expf(lrelu(a_s[sidx] + adn));
        }
        int u = 0;
        for (; u + 8 <= cnt; u += 8) {
            int s0 = __shfl(sidx, u + 0), s1 = __shfl(sidx, u + 1);
            int s2 = __shfl(sidx, u + 2), s3 = __shfl(sidx, u + 3);
            int s4 = __shfl(sidx, u + 4), s5 = __shfl(sidx, u + 5);
            int s6 = __shfl(sidx, u + 6), s7 = __shfl(sidx, u + 7);
            float p0 = __shfl(pe, u + 0), p1 = __shfl(pe, u + 1);
            float p2 = __shfl(pe, u + 2), p3 = __shfl(pe, u + 3);
            float p4 = __shfl(pe, u + 4), p5 = __shfl(pe, u + 5);
            float p6 = __shfl(pe, u + 6), p7 = __shfl(pe, u + 7);
            float v0 = (float)xs[(long)s0 * OUT_CH + lane];
            float v1 = (float)xs[(long)s1 * OUT_CH + lane];
            float v2 = (float)xs[(long)s2 * OUT_CH + lane];
            float v3 = (float)xs[(long)s3 * OUT_CH + lane];
            float v4 = (float)xs[(long)s4 * OUT_CH + lane];
            float v5 = (float)xs[(long)s5 * OUT_CH + lane];
            float v6 = (float)xs[(long)s6 * OUT_CH + lane];
            float v7 = (float)xs[(long)s7 * OUT_CH + lane];
            den += ((p0 + p1) + (p2 + p3)) + ((p4 + p5) + (p6 + p7));
            acc += p0 * v0 + p1 * v1 + p2 * v2 + p3 * v3
                 + p4 * v4 + p5 * v5 + p6 * v6 + p7 * v7;
        }
        for (; u < cnt; ++u) {
            int s = __shfl(sidx, u);
            float p = __shfl(pe, u);
            den += p;
            acc += p * (float)xs[(long)s * OUT_CH + lane];
        }
    }
    out[(long)n * OUT_CH + lane] = acc / den + bias[lane];
}

// ---------------- launch ----------------

extern "C" void kernel_launch(void* const* d_in, const int* in_sizes, int n_in,
                              void* d_out, int out_size, void* d_ws, size_t ws_size,
                              hipStream_t stream) {
    const float* x     = (const float*)d_in[0];
    const int*   ei    = (const int*)d_in[1];      // int32 edge index [2, E]
    const float* W1    = (const float*)d_in[2];
    const float* atts1 = (const float*)d_in[3];
    const float* attd1 = (const float*)d_in[4];
    const float* bias1 = (const float*)d_in[5];
    const float* W2    = (const float*)d_in[6];
    const float* atts2 = (const float*)d_in[7];
    const float* attd2 = (const float*)d_in[8];
    const float* bias2 = (const float*)d_in[9];
    float*       out   = (float*)d_out;

    const int* srcp = ei;
    const int* dstp = ei + NE;

    char* ws = (char*)d_ws;
    size_t off = 0;
    auto alloc = [&](size_t bytes) -> void* {
        void* p = ws + off;
        off += (bytes + 255) & ~(size_t)255;
        return p;
    };
    _Float16* xs1h  = (_Float16*)alloc((size_t)NN * HC * 2);  // 25.6 MB
    float*    h1    = (float*)alloc((size_t)NN * HC * 4);     // 51.2 MB
    float*    as1   = (float*)alloc((size_t)NN * HEADS * 4);  // 1.6 MB
    float*    ad1   = (float*)alloc((size_t)NN * HEADS * 4);  // 1.6 MB
    int*   deg      = (int*)alloc((size_t)NN * 4);
    int*   offsets  = (int*)alloc((size_t)(NN + 1) * 4);
    int*   cursor   = (int*)alloc((size_t)NN * 4);
    int*   ssrc     = (int*)alloc((size_t)NE * 4);            // 3.2 MB
    // layer-2 scratch aliases layer-1 buffers dead after agg1:
    _Float16* xs2h = xs1h;     // [NN,64] fp16 <= [NN,256] fp16 space
    float*    as2  = as1;
    float*    ad2  = ad1;

    // --- CSR build (counting sort by dst) ---
    hipMemsetAsync(deg, 0, (size_t)NN * 4, stream);
    hist_kernel<<<(NE + 255) / 256, 256, 0, stream>>>(dstp, deg);
    scan_kernel<<<1, 1024, 0, stream>>>(deg, offsets, cursor);
    scatter_kernel<<<(NE + 255) / 256, 256, 0, stream>>>(srcp, dstp, cursor, ssrc);

    // --- layer 1 ---
    {
        dim3 grid((NN + 127) / 128, HC / 128);
        gemm_f32_128_h<<<grid, 256, 0, stream>>>(x, W1, xs1h, NN, HC, IN_CH);
    }
    attcoef1<<<(NN * HEADS + 255) / 256, 256, 0, stream>>>(xs1h, atts1, attd1, as1, ad1);
    agg1<<<(NN + 3) / 4, 256, 0, stream>>>(xs1h, as1, ad1, offsets, ssrc, bias1, h1);

    // --- layer 2 ---
    {
        dim3 grid((NN + 63) / 64, OUT_CH / 64);
        gemm_f32_h<<<grid, 256, 0, stream>>>(h1, W2, xs2h, NN, OUT_CH, HC);
    }
    attcoef2<<<(NN + 255) / 256, 256, 0, stream>>>(xs2h, atts2, attd2, as2, ad2);
    agg2<<<(NN + 3) / 4, 256, 0, stream>>>(xs2h, as2, ad2, offsets, ssrc, bias2, out);
}

// Round 7
// 381.588 us; speedup vs baseline: 1.7229x; 1.2504x over previous
//
#include <hip/hip_runtime.h>

#define NN 50000
#define NE 800000
#define IN_CH 128
#define HID 32
#define HEADS 8
#define HC 256          // HEADS*HID
#define OUT_CH 64
#define NEG_SLOPE 0.2f
#define SCAN_BLOCKS 196  // 196*256 = 50176 >= NN

typedef _Float16 half4 __attribute__((ext_vector_type(4)));
typedef _Float16 half8 __attribute__((ext_vector_type(8)));

// ---------------- counting sort (CSR by dst) ----------------

__global__ void hist_kernel(const int* __restrict__ dst, int* __restrict__ deg) {
    int e = blockIdx.x * blockDim.x + threadIdx.x;
    if (e < NE) atomicAdd(&deg[dst[e]], 1);
}

// 3-phase hierarchical scan (replaces the 110us single-block scan: one CU,
// 49 serial loads/thread -> GPU idle; now ~10us across 3 wide launches).
__global__ __launch_bounds__(256)
void scan_phase1(const int* __restrict__ deg, int* __restrict__ excl,
                 int* __restrict__ bsum) {
    __shared__ int sm[256];
    const int t = blockIdx.x * 256 + threadIdx.x;
    const int v = (t < NN) ? deg[t] : 0;
    sm[threadIdx.x] = v;
    __syncthreads();
    for (int off = 1; off < 256; off <<= 1) {
        int u = (threadIdx.x >= off) ? sm[threadIdx.x - off] : 0;
        __syncthreads();
        sm[threadIdx.x] += u;
        __syncthreads();
    }
    if (t < NN) excl[t] = sm[threadIdx.x] - v;      // exclusive within block
    if (threadIdx.x == 255) bsum[blockIdx.x] = sm[255];
}

__global__ __launch_bounds__(256)
void scan_phase2(const int* __restrict__ bsum, int* __restrict__ boff,
                 int* __restrict__ offsets) {
    __shared__ int sm[256];
    const int t = threadIdx.x;
    const int v = (t < SCAN_BLOCKS) ? bsum[t] : 0;
    sm[t] = v;
    __syncthreads();
    for (int off = 1; off < 256; off <<= 1) {
        int u = (t >= off) ? sm[t - off] : 0;
        __syncthreads();
        sm[t] += u;
        __syncthreads();
    }
    if (t < SCAN_BLOCKS) boff[t] = sm[t] - v;       // exclusive block offset
    if (t == 255) offsets[NN] = sm[255];            // grand total (== NE)
}

__global__ __launch_bounds__(256)
void scan_phase3(const int* __restrict__ excl, const int* __restrict__ boff,
                 int* __restrict__ offsets, int* __restrict__ cursor) {
    const int t = blockIdx.x * 256 + threadIdx.x;
    if (t < NN) {
        int v = excl[t] + boff[blockIdx.x];
        offsets[t] = v;
        cursor[t]  = v;
    }
}

__global__ void scatter_kernel(const int* __restrict__ src,
                               const int* __restrict__ dst,
                               int* __restrict__ cursor, int* __restrict__ ssrc) {
    int e = blockIdx.x * blockDim.x + threadIdx.x;
    if (e < NE) {
        int d = dst[e];
        int pos = atomicAdd(&cursor[d], 1);
        ssrc[pos] = src[e];
    }
}

// ---------------- f32 GEMM, 128x128 tile, fp16 output (layer 1) ----------------
__global__ __launch_bounds__(256)
void gemm_f32_128_h(const float* __restrict__ A, const float* __restrict__ B,
                    _Float16* __restrict__ C, int M, int N, int K) {
    __shared__ float As[16][128 + 4];
    __shared__ float Bs[16][128];
    const int tid = threadIdx.x;
    const int bm = blockIdx.x * 128;
    const int bn = blockIdx.y * 128;
    const int tx = tid & 15;
    const int ty = tid >> 4;

    float acc[8][8] = {};
    for (int k0 = 0; k0 < K; k0 += 16) {
#pragma unroll
        for (int it = 0; it < 2; ++it) {
            int idx = tid + it * 256;
            int r = idx >> 2;
            int c = (idx & 3) * 4;
            float4 av = make_float4(0.f, 0.f, 0.f, 0.f);
            int ar = bm + r;
            if (ar < M) av = *(const float4*)(A + (long)ar * K + k0 + c);
            As[c + 0][r] = av.x;
            As[c + 1][r] = av.y;
            As[c + 2][r] = av.z;
            As[c + 3][r] = av.w;
        }
#pragma unroll
        for (int it = 0; it < 2; ++it) {
            int idx = tid + it * 256;
            int r = idx >> 5;
            int c = (idx & 31) * 4;
            *(float4*)&Bs[r][c] = *(const float4*)(B + (long)(k0 + r) * N + bn + c);
        }
        __syncthreads();
#pragma unroll
        for (int kk = 0; kk < 16; ++kk) {
            float a[8], b[8];
            *(float4*)&a[0] = *(const float4*)&As[kk][ty * 4];
            *(float4*)&a[4] = *(const float4*)&As[kk][64 + ty * 4];
            *(float4*)&b[0] = *(const float4*)&Bs[kk][tx * 4];
            *(float4*)&b[4] = *(const float4*)&Bs[kk][64 + tx * 4];
#pragma unroll
            for (int i = 0; i < 8; ++i)
#pragma unroll
                for (int j = 0; j < 8; ++j) acc[i][j] += a[i] * b[j];
        }
        __syncthreads();
    }
#pragma unroll
    for (int ih = 0; ih < 2; ++ih)
#pragma unroll
    for (int i4 = 0; i4 < 4; ++i4) {
        int r = bm + ih * 64 + ty * 4 + i4;
        if (r >= M) continue;
        int i = ih * 4 + i4;
#pragma unroll
        for (int jh = 0; jh < 2; ++jh) {
            half4 hv;
            hv[0] = (_Float16)acc[i][jh * 4 + 0];
            hv[1] = (_Float16)acc[i][jh * 4 + 1];
            hv[2] = (_Float16)acc[i][jh * 4 + 2];
            hv[3] = (_Float16)acc[i][jh * 4 + 3];
            *(half4*)(C + (long)r * N + bn + jh * 64 + tx * 4) = hv;
        }
    }
}

// ---------------- f32 GEMM, 64x64 tile, fp16 output (layer 2) ----------------
__global__ __launch_bounds__(256)
void gemm_f32_h(const float* __restrict__ A, const float* __restrict__ B,
                _Float16* __restrict__ C, int M, int N, int K) {
    __shared__ float As[16][64 + 4];
    __shared__ float Bs[16][64];
    const int tid = threadIdx.x;
    const int bm = blockIdx.x * 64;
    const int bn = blockIdx.y * 64;
    const int tx = tid % 16;
    const int ty = tid / 16;
    const int arow = tid / 4;
    const int acol = (tid % 4) * 4;
    const int brow = tid / 16;
    const int bcol = (tid % 16) * 4;

    float acc[4][4] = {};
    for (int k0 = 0; k0 < K; k0 += 16) {
        float4 av = make_float4(0.f, 0.f, 0.f, 0.f);
        int ar = bm + arow;
        if (ar < M) av = *(const float4*)(A + (long)ar * K + k0 + acol);
        As[acol + 0][arow] = av.x;
        As[acol + 1][arow] = av.y;
        As[acol + 2][arow] = av.z;
        As[acol + 3][arow] = av.w;
        float4 bv = *(const float4*)(B + (long)(k0 + brow) * N + bn + bcol);
        *(float4*)&Bs[brow][bcol] = bv;
        __syncthreads();
#pragma unroll
        for (int kk = 0; kk < 16; ++kk) {
            float a[4], b[4];
#pragma unroll
            for (int i = 0; i < 4; ++i) a[i] = As[kk][ty * 4 + i];
#pragma unroll
            for (int j = 0; j < 4; ++j) b[j] = Bs[kk][tx * 4 + j];
#pragma unroll
            for (int i = 0; i < 4; ++i)
#pragma unroll
                for (int j = 0; j < 4; ++j) acc[i][j] += a[i] * b[j];
        }
        __syncthreads();
    }
#pragma unroll
    for (int i = 0; i < 4; ++i) {
        int r = bm + ty * 4 + i;
        if (r < M) {
            half4 hv;
            hv[0] = (_Float16)acc[i][0];
            hv[1] = (_Float16)acc[i][1];
            hv[2] = (_Float16)acc[i][2];
            hv[3] = (_Float16)acc[i][3];
            *(half4*)(C + (long)r * N + bn + tx * 4) = hv;
        }
    }
}

// ---------------- attention coefficients (fp16 features, f32 math) ----------------

__global__ void attcoef1(const _Float16* __restrict__ xs, const float* __restrict__ att_s,
                         const float* __restrict__ att_d,
                         float* __restrict__ a_s, float* __restrict__ a_d) {
    int idx = blockIdx.x * blockDim.x + threadIdx.x;   // n*8 + h
    if (idx >= NN * HEADS) return;
    int h = idx & 7;
    const _Float16* xp = xs + (long)idx * 32;
    const float* sp = att_s + h * 32;
    const float* dp = att_d + h * 32;
    float as = 0.f, ad = 0.f;
#pragma unroll
    for (int i = 0; i < 4; ++i) {
        half8 v = *(const half8*)(xp + i * 8);
#pragma unroll
        for (int j = 0; j < 8; ++j) {
            float f = (float)v[j];
            as += f * sp[i * 8 + j];
            ad += f * dp[i * 8 + j];
        }
    }
    a_s[idx] = as;
    a_d[idx] = ad;
}

__global__ void attcoef2(const _Float16* __restrict__ xs, const float* __restrict__ att_s,
                         const float* __restrict__ att_d,
                         float* __restrict__ a_s, float* __restrict__ a_d) {
    int n = blockIdx.x * blockDim.x + threadIdx.x;
    if (n >= NN) return;
    const _Float16* xp = xs + (long)n * 64;
    float as = 0.f, ad = 0.f;
#pragma unroll
    for (int i = 0; i < 8; ++i) {
        half8 v = *(const half8*)(xp + i * 8);
#pragma unroll
        for (int j = 0; j < 8; ++j) {
            float f = (float)v[j];
            as += f * att_s[i * 8 + j];
            ad += f * att_d[i * 8 + j];
        }
    }
    a_s[n] = as;
    a_d[n] = ad;
}

// ---------------- aggregation (gather, CSR, single-pass softmax) ----------------

__device__ __forceinline__ float lrelu(float x) { return x > 0.f ? x : NEG_SLOPE * x; }

__global__ __launch_bounds__(256)
void agg1(const _Float16* __restrict__ xs, const float* __restrict__ a_s,
          const float* __restrict__ a_d, const int* __restrict__ offsets,
          const int* __restrict__ ssrc, const float* __restrict__ bias,
          float* __restrict__ out) {
    __shared__ float pl_all[4][64 * 9];
    const int wslot = threadIdx.x >> 6;
    const int wave = (blockIdx.x * blockDim.x + threadIdx.x) >> 6;
    const int lane = threadIdx.x & 63;
    if (wave >= NN) return;
    float* pl = pl_all[wslot];
    const int n = wave;
    const int h = lane >> 3;
    const int ch = h * 32 + (lane & 7) * 4;

    const float4 D0 = *(const float4*)(a_d + (long)n * 8);
    const float4 D1 = *(const float4*)(a_d + (long)n * 8 + 4);
    const float adn = a_d[n * 8 + h];
    const int beg = offsets[n], end = offsets[n + 1];

    float pself = __expf(lrelu(a_s[n * 8 + h] + adn));
    float den = pself;
    float ax, ay, az, aw;
    {
        half4 v = *(const half4*)(xs + (long)n * HC + ch);
        ax = pself * (float)v[0]; ay = pself * (float)v[1];
        az = pself * (float)v[2]; aw = pself * (float)v[3];
    }

    for (int base = beg; base < end; base += 64) {
        const int cnt = min(64, end - base);
        int sidx = 0;
        if (lane < cnt) {
            sidx = ssrc[base + lane];
            const float4* ap = (const float4*)(a_s + (long)sidx * 8);
            float4 A0 = ap[0], A1 = ap[1];
            pl[lane * 9 + 0] = __expf(lrelu(A0.x + D0.x));
            pl[lane * 9 + 1] = __expf(lrelu(A0.y + D0.y));
            pl[lane * 9 + 2] = __expf(lrelu(A0.z + D0.z));
            pl[lane * 9 + 3] = __expf(lrelu(A0.w + D0.w));
            pl[lane * 9 + 4] = __expf(lrelu(A1.x + D1.x));
            pl[lane * 9 + 5] = __expf(lrelu(A1.y + D1.y));
            pl[lane * 9 + 6] = __expf(lrelu(A1.z + D1.z));
            pl[lane * 9 + 7] = __expf(lrelu(A1.w + D1.w));
        }
        // order LDS writes before cross-lane reads; wave-internal (no __syncthreads:
        // waves are divergent per node and would deadlock).
        asm volatile("s_waitcnt lgkmcnt(0)" ::: "memory");

        int u = 0;
        for (; u + 8 <= cnt; u += 8) {
            int s0 = __shfl(sidx, u + 0), s1 = __shfl(sidx, u + 1);
            int s2 = __shfl(sidx, u + 2), s3 = __shfl(sidx, u + 3);
            int s4 = __shfl(sidx, u + 4), s5 = __shfl(sidx, u + 5);
            int s6 = __shfl(sidx, u + 6), s7 = __shfl(sidx, u + 7);
            half4 v0 = *(const half4*)(xs + (long)s0 * HC + ch);
            half4 v1 = *(const half4*)(xs + (long)s1 * HC + ch);
            half4 v2 = *(const half4*)(xs + (long)s2 * HC + ch);
            half4 v3 = *(const half4*)(xs + (long)s3 * HC + ch);
            half4 v4 = *(const half4*)(xs + (long)s4 * HC + ch);
            half4 v5 = *(const half4*)(xs + (long)s5 * HC + ch);
            half4 v6 = *(const half4*)(xs + (long)s6 * HC + ch);
            half4 v7 = *(const half4*)(xs + (long)s7 * HC + ch);
            float p0 = pl[(u + 0) * 9 + h], p1 = pl[(u + 1) * 9 + h];
            float p2 = pl[(u + 2) * 9 + h], p3 = pl[(u + 3) * 9 + h];
            float p4 = pl[(u + 4) * 9 + h], p5 = pl[(u + 5) * 9 + h];
            float p6 = pl[(u + 6) * 9 + h], p7 = pl[(u + 7) * 9 + h];
            den += ((p0 + p1) + (p2 + p3)) + ((p4 + p5) + (p6 + p7));
            ax += p0 * (float)v0[0] + p1 * (float)v1[0] + p2 * (float)v2[0] + p3 * (float)v3[0]
                + p4 * (float)v4[0] + p5 * (float)v5[0] + p6 * (float)v6[0] + p7 * (float)v7[0];
            ay += p0 * (float)v0[1] + p1 * (float)v1[1] + p2 * (float)v2[1] + p3 * (float)v3[1]
                + p4 * (float)v4[1] + p5 * (float)v5[1] + p6 * (float)v6[1] + p7 * (float)v7[1];
            az += p0 * (float)v0[2] + p1 * (float)v1[2] + p2 * (float)v2[2] + p3 * (float)v3[2]
                + p4 * (float)v4[2] + p5 * (float)v5[2] + p6 * (float)v6[2] + p7 * (float)v7[2];
            aw += p0 * (float)v0[3] + p1 * (float)v1[3] + p2 * (float)v2[3] + p3 * (float)v3[3]
                + p4 * (float)v4[3] + p5 * (float)v5[3] + p6 * (float)v6[3] + p7 * (float)v7[3];
        }
        for (; u < cnt; ++u) {
            int s = __shfl(sidx, u);
            float p = pl[u * 9 + h];
            half4 v = *(const half4*)(xs + (long)s * HC + ch);
            den += p;
            ax += p * (float)v[0]; ay += p * (float)v[1];
            az += p * (float)v[2]; aw += p * (float)v[3];
        }
    }
    float inv = 1.0f / den;
    float4 b = *(const float4*)(bias + ch);
    float4 o;
    o.x = ax * inv + b.x; o.y = ay * inv + b.y;
    o.z = az * inv + b.z; o.w = aw * inv + b.w;
    // ELU
    o.x = o.x > 0.f ? o.x : expm1f(o.x);
    o.y = o.y > 0.f ? o.y : expm1f(o.y);
    o.z = o.z > 0.f ? o.z : expm1f(o.z);
    o.w = o.w > 0.f ? o.w : expm1f(o.w);
    *(float4*)(out + (long)n * HC + ch) = o;
}

// layer 2: H=1, C=64; scores via shfl; fp16 rows of 128B.
__global__ __launch_bounds__(256)
void agg2(const _Float16* __restrict__ xs, const float* __restrict__ a_s,
          const float* __restrict__ a_d, const int* __restrict__ offsets,
          const int* __restrict__ ssrc, const float* __restrict__ bias,
          float* __restrict__ out) {
    const int wave = (blockIdx.x * blockDim.x + threadIdx.x) >> 6;
    const int lane = threadIdx.x & 63;
    if (wave >= NN) return;
    const int n = wave;

    const float adn = a_d[n];
    const int beg = offsets[n], end = offsets[n + 1];

    float pself = __expf(lrelu(a_s[n] + adn));
    float den = pself;
    float acc = pself * (float)xs[(long)n * OUT_CH + lane];

    for (int base = beg; base < end; base += 64) {
        const int cnt = min(64, end - base);
        int sidx = 0;
        float pe = 0.f;
        if (lane < cnt) {
            sidx = ssrc[base + lane];
            pe = __expf(lrelu(a_s[sidx] + adn));
        }
        int u = 0;
        for (; u + 8 <= cnt; u += 8) {
            int s0 = __shfl(sidx, u + 0), s1 = __shfl(sidx, u + 1);
            int s2 = __shfl(sidx, u + 2), s3 = __shfl(sidx, u + 3);
            int s4 = __shfl(sidx, u + 4), s5 = __shfl(sidx, u + 5);
            int s6 = __shfl(sidx, u + 6), s7 = __shfl(sidx, u + 7);
            float p0 = __shfl(pe, u + 0), p1 = __shfl(pe, u + 1);
            float p2 = __shfl(pe, u + 2), p3 = __shfl(pe, u + 3);
            float p4 = __shfl(pe, u + 4), p5 = __shfl(pe, u + 5);
            float p6 = __shfl(pe, u + 6), p7 = __shfl(pe, u + 7);
            float v0 = (float)xs[(long)s0 * OUT_CH + lane];
            float v1 = (float)xs[(long)s1 * OUT_CH + lane];
            float v2 = (float)xs[(long)s2 * OUT_CH + lane];
            float v3 = (float)xs[(long)s3 * OUT_CH + lane];
            float v4 = (float)xs[(long)s4 * OUT_CH + lane];
            float v5 = (float)xs[(long)s5 * OUT_CH + lane];
            float v6 = (float)xs[(long)s6 * OUT_CH + lane];
            float v7 = (float)xs[(long)s7 * OUT_CH + lane];
            den += ((p0 + p1) + (p2 + p3)) + ((p4 + p5) + (p6 + p7));
            acc += p0 * v0 + p1 * v1 + p2 * v2 + p3 * v3
                 + p4 * v4 + p5 * v5 + p6 * v6 + p7 * v7;
        }
        for (; u < cnt; ++u) {
            int s = __shfl(sidx, u);
            float p = __shfl(pe, u);
            den += p;
            acc += p * (float)xs[(long)s * OUT_CH + lane];
        }
    }
    out[(long)n * OUT_CH + lane] = acc / den + bias[lane];
}

// ---------------- launch ----------------

extern "C" void kernel_launch(void* const* d_in, const int* in_sizes, int n_in,
                              void* d_out, int out_size, void* d_ws, size_t ws_size,
                              hipStream_t stream) {
    const float* x     = (const float*)d_in[0];
    const int*   ei    = (const int*)d_in[1];      // int32 edge index [2, E]
    const float* W1    = (const float*)d_in[2];
    const float* atts1 = (const float*)d_in[3];
    const float* attd1 = (const float*)d_in[4];
    const float* bias1 = (const float*)d_in[5];
    const float* W2    = (const float*)d_in[6];
    const float* atts2 = (const float*)d_in[7];
    const float* attd2 = (const float*)d_in[8];
    const float* bias2 = (const float*)d_in[9];
    float*       out   = (float*)d_out;

    const int* srcp = ei;
    const int* dstp = ei + NE;

    char* ws = (char*)d_ws;
    size_t off = 0;
    auto alloc = [&](size_t bytes) -> void* {
        void* p = ws + off;
        off += (bytes + 255) & ~(size_t)255;
        return p;
    };
    _Float16* xs1h  = (_Float16*)alloc((size_t)NN * HC * 2);  // 25.6 MB
    float*    h1    = (float*)alloc((size_t)NN * HC * 4);     // 51.2 MB
    float*    as1   = (float*)alloc((size_t)NN * HEADS * 4);  // 1.6 MB
    float*    ad1   = (float*)alloc((size_t)NN * HEADS * 4);  // 1.6 MB
    int*   deg      = (int*)alloc((size_t)NN * 4);
    int*   offsets  = (int*)alloc((size_t)(NN + 1) * 4);
    int*   cursor   = (int*)alloc((size_t)NN * 4);
    int*   ssrc     = (int*)alloc((size_t)NE * 4);            // 3.2 MB
    int*   excl     = (int*)alloc((size_t)NN * 4);
    int*   bsum     = (int*)alloc((size_t)SCAN_BLOCKS * 4);
    int*   boff     = (int*)alloc((size_t)SCAN_BLOCKS * 4);
    // layer-2 scratch aliases layer-1 buffers dead after agg1:
    _Float16* xs2h = xs1h;
    float*    as2  = as1;
    float*    ad2  = ad1;

    // --- CSR build (counting sort by dst, 3-phase parallel scan) ---
    hipMemsetAsync(deg, 0, (size_t)NN * 4, stream);
    hist_kernel<<<(NE + 255) / 256, 256, 0, stream>>>(dstp, deg);
    scan_phase1<<<SCAN_BLOCKS, 256, 0, stream>>>(deg, excl, bsum);
    scan_phase2<<<1, 256, 0, stream>>>(bsum, boff, offsets);
    scan_phase3<<<SCAN_BLOCKS, 256, 0, stream>>>(excl, boff, offsets, cursor);
    scatter_kernel<<<(NE + 255) / 256, 256, 0, stream>>>(srcp, dstp, cursor, ssrc);

    // --- layer 1 ---
    {
        dim3 grid((NN + 127) / 128, HC / 128);
        gemm_f32_128_h<<<grid, 256, 0, stream>>>(x, W1, xs1h, NN, HC, IN_CH);
    }
    attcoef1<<<(NN * HEADS + 255) / 256, 256, 0, stream>>>(xs1h, atts1, attd1, as1, ad1);
    agg1<<<(NN + 3) / 4, 256, 0, stream>>>(xs1h, as1, ad1, offsets, ssrc, bias1, h1);

    // --- layer 2 ---
    {
        dim3 grid((NN + 63) / 64, OUT_CH / 64);
        gemm_f32_h<<<grid, 256, 0, stream>>>(h1, W2, xs2h, NN, OUT_CH, HC);
    }
    attcoef2<<<(NN + 255) / 256, 256, 0, stream>>>(xs2h, atts2, attd2, as2, ad2);
    agg2<<<(NN + 3) / 4, 256, 0, stream>>>(xs2h, as2, ad2, offsets, ssrc, bias2, out);
}

// Round 8
// 324.920 us; speedup vs baseline: 2.0234x; 1.1744x over previous
//
#include <hip/hip_runtime.h>

#define NN 50000
#define NE 800000
#define IN_CH 128
#define HID 32
#define HEADS 8
#define HC 256          // HEADS*HID
#define OUT_CH 64
#define NEG_SLOPE 0.2f
#define SCAN_BLOCKS 196  // 196*256 = 50176 >= NN

typedef _Float16 half4 __attribute__((ext_vector_type(4)));
typedef _Float16 half8 __attribute__((ext_vector_type(8)));
typedef float    f32x4 __attribute__((ext_vector_type(4)));

// ---------------- counting sort (CSR by dst) ----------------

__global__ void hist_kernel(const int* __restrict__ dst, int* __restrict__ deg) {
    int e = blockIdx.x * blockDim.x + threadIdx.x;
    if (e < NE) atomicAdd(&deg[dst[e]], 1);
}

__global__ __launch_bounds__(256)
void scan_phase1(const int* __restrict__ deg, int* __restrict__ excl,
                 int* __restrict__ bsum) {
    __shared__ int sm[256];
    const int t = blockIdx.x * 256 + threadIdx.x;
    const int v = (t < NN) ? deg[t] : 0;
    sm[threadIdx.x] = v;
    __syncthreads();
    for (int off = 1; off < 256; off <<= 1) {
        int u = (threadIdx.x >= off) ? sm[threadIdx.x - off] : 0;
        __syncthreads();
        sm[threadIdx.x] += u;
        __syncthreads();
    }
    if (t < NN) excl[t] = sm[threadIdx.x] - v;
    if (threadIdx.x == 255) bsum[blockIdx.x] = sm[255];
}

__global__ __launch_bounds__(256)
void scan_phase2(const int* __restrict__ bsum, int* __restrict__ boff,
                 int* __restrict__ offsets) {
    __shared__ int sm[256];
    const int t = threadIdx.x;
    const int v = (t < SCAN_BLOCKS) ? bsum[t] : 0;
    sm[t] = v;
    __syncthreads();
    for (int off = 1; off < 256; off <<= 1) {
        int u = (t >= off) ? sm[t - off] : 0;
        __syncthreads();
        sm[t] += u;
        __syncthreads();
    }
    if (t < SCAN_BLOCKS) boff[t] = sm[t] - v;
    if (t == 255) offsets[NN] = sm[255];
}

__global__ __launch_bounds__(256)
void scan_phase3(const int* __restrict__ excl, const int* __restrict__ boff,
                 int* __restrict__ offsets, int* __restrict__ cursor) {
    const int t = blockIdx.x * 256 + threadIdx.x;
    if (t < NN) {
        int v = excl[t] + boff[blockIdx.x];
        offsets[t] = v;
        cursor[t]  = v;
    }
}

__global__ void scatter_kernel(const int* __restrict__ src,
                               const int* __restrict__ dst,
                               int* __restrict__ cursor, int* __restrict__ ssrc) {
    int e = blockIdx.x * blockDim.x + threadIdx.x;
    if (e < NE) {
        int d = dst[e];
        int pos = atomicAdd(&cursor[d], 1);
        ssrc[pos] = src[e];
    }
}

// ---------------- fp16 prep ----------------

__global__ void cast_f32_f16(const float* __restrict__ in, _Float16* __restrict__ out,
                             int n8) {
    int i = blockIdx.x * blockDim.x + threadIdx.x;
    if (i >= n8) return;
    float4 a = ((const float4*)in)[i * 2];
    float4 b = ((const float4*)in)[i * 2 + 1];
    half8 h;
    h[0] = (_Float16)a.x; h[1] = (_Float16)a.y; h[2] = (_Float16)a.z; h[3] = (_Float16)a.w;
    h[4] = (_Float16)b.x; h[5] = (_Float16)b.y; h[6] = (_Float16)b.z; h[7] = (_Float16)b.w;
    ((half8*)out)[i] = h;
}

// Wt[n][k] = (fp16) W[k][n]
__global__ void transpose_cast(const float* __restrict__ W, _Float16* __restrict__ Wt,
                               int K, int N) {
    int i = blockIdx.x * blockDim.x + threadIdx.x;
    if (i >= K * N) return;
    int k = i / N, n = i - k * N;
    Wt[(size_t)n * K + k] = (_Float16)W[i];
}

// ---------------- MFMA fp16 GEMM ----------------
// C[M,N] = A[M,K] * B[K,N]; A row-major fp16, Bt = B^T row-major fp16 [N][K].
// 64x64 block tile, 4 waves; wave w computes rows [16w,16w+16) x 64 cols as
// 4 accumulators. K staged in 128-chunks: Asl/Btl [64][136] fp16 (pad 136 ->
// ds_read_b128 at 2-way bank aliasing = free). Fragment mapping (m89-verified):
// D: col=lane&15, row=(lane>>4)*4+reg; A/B: lane holds 8 contiguous k at
// k-base (lane>>4)*8, row/col = lane&15.
__global__ __launch_bounds__(256)
void gemm_mfma_h(const _Float16* __restrict__ A, const _Float16* __restrict__ Bt,
                 _Float16* __restrict__ C, int M, int N, int K) {
    __shared__ _Float16 Asl[64][136];
    __shared__ _Float16 Btl[64][136];
    const int tid  = threadIdx.x;
    const int wave = tid >> 6, lane = tid & 63;
    const int lr = lane & 15, lk = lane >> 4;
    const int bm = blockIdx.x * 64, bn = blockIdx.y * 64;
    const int sr = tid >> 2;            // staging row 0..63
    const int ss = (tid & 3) * 32;      // staging k-segment

    f32x4 acc[4];
#pragma unroll
    for (int i = 0; i < 4; ++i) acc[i] = (f32x4){0.f, 0.f, 0.f, 0.f};

    for (int k0 = 0; k0 < K; k0 += 128) {
        {
            const int ar = bm + sr;
            half8 v0 = {}, v1 = {}, v2 = {}, v3 = {};
            if (ar < M) {
                const half8* ga = (const half8*)(A + (size_t)ar * K + k0 + ss);
                v0 = ga[0]; v1 = ga[1]; v2 = ga[2]; v3 = ga[3];
            }
            *(half8*)&Asl[sr][ss + 0]  = v0;
            *(half8*)&Asl[sr][ss + 8]  = v1;
            *(half8*)&Asl[sr][ss + 16] = v2;
            *(half8*)&Asl[sr][ss + 24] = v3;
            const half8* gb = (const half8*)(Bt + (size_t)(bn + sr) * K + k0 + ss);
            half8 w0 = gb[0], w1 = gb[1], w2 = gb[2], w3 = gb[3];
            *(half8*)&Btl[sr][ss + 0]  = w0;
            *(half8*)&Btl[sr][ss + 8]  = w1;
            *(half8*)&Btl[sr][ss + 16] = w2;
            *(half8*)&Btl[sr][ss + 24] = w3;
        }
        __syncthreads();
#pragma unroll
        for (int kk = 0; kk < 128; kk += 32) {
            half8 a = *(const half8*)&Asl[wave * 16 + lr][kk + lk * 8];
#pragma unroll
            for (int nt = 0; nt < 4; ++nt) {
                half8 b = *(const half8*)&Btl[nt * 16 + lr][kk + lk * 8];
                acc[nt] = __builtin_amdgcn_mfma_f32_16x16x32_f16(a, b, acc[nt], 0, 0, 0);
            }
        }
        __syncthreads();
    }
#pragma unroll
    for (int nt = 0; nt < 4; ++nt) {
        const int col = bn + nt * 16 + lr;
#pragma unroll
        for (int r = 0; r < 4; ++r) {
            const int m = bm + wave * 16 + lk * 4 + r;
            if (m < M) C[(size_t)m * N + col] = (_Float16)acc[nt][r];
        }
    }
}

// ---------------- attention coefficients (fp16 features, f32 math) ----------------

__global__ void attcoef1(const _Float16* __restrict__ xs, const float* __restrict__ att_s,
                         const float* __restrict__ att_d,
                         float* __restrict__ a_s, float* __restrict__ a_d) {
    int idx = blockIdx.x * blockDim.x + threadIdx.x;   // n*8 + h
    if (idx >= NN * HEADS) return;
    int h = idx & 7;
    const _Float16* xp = xs + (long)idx * 32;
    const float* sp = att_s + h * 32;
    const float* dp = att_d + h * 32;
    float as = 0.f, ad = 0.f;
#pragma unroll
    for (int i = 0; i < 4; ++i) {
        half8 v = *(const half8*)(xp + i * 8);
#pragma unroll
        for (int j = 0; j < 8; ++j) {
            float f = (float)v[j];
            as += f * sp[i * 8 + j];
            ad += f * dp[i * 8 + j];
        }
    }
    a_s[idx] = as;
    a_d[idx] = ad;
}

__global__ void attcoef2(const _Float16* __restrict__ xs, const float* __restrict__ att_s,
                         const float* __restrict__ att_d,
                         float* __restrict__ a_s, float* __restrict__ a_d) {
    int n = blockIdx.x * blockDim.x + threadIdx.x;
    if (n >= NN) return;
    const _Float16* xp = xs + (long)n * 64;
    float as = 0.f, ad = 0.f;
#pragma unroll
    for (int i = 0; i < 8; ++i) {
        half8 v = *(const half8*)(xp + i * 8);
#pragma unroll
        for (int j = 0; j < 8; ++j) {
            float f = (float)v[j];
            as += f * att_s[i * 8 + j];
            ad += f * att_d[i * 8 + j];
        }
    }
    a_s[n] = as;
    a_d[n] = ad;
}

// ---------------- aggregation (gather, CSR, single-pass softmax) ----------------

__device__ __forceinline__ float lrelu(float x) { return x > 0.f ? x : NEG_SLOPE * x; }

// layer 1: out is fp16 (feeds MFMA gemm2). ELU+bias in f32, cast on store.
__global__ __launch_bounds__(256)
void agg1(const _Float16* __restrict__ xs, const float* __restrict__ a_s,
          const float* __restrict__ a_d, const int* __restrict__ offsets,
          const int* __restrict__ ssrc, const float* __restrict__ bias,
          _Float16* __restrict__ out) {
    __shared__ float pl_all[4][64 * 9];
    const int wslot = threadIdx.x >> 6;
    const int wave = (blockIdx.x * blockDim.x + threadIdx.x) >> 6;
    const int lane = threadIdx.x & 63;
    if (wave >= NN) return;
    float* pl = pl_all[wslot];
    const int n = wave;
    const int h = lane >> 3;
    const int ch = h * 32 + (lane & 7) * 4;

    const float4 D0 = *(const float4*)(a_d + (long)n * 8);
    const float4 D1 = *(const float4*)(a_d + (long)n * 8 + 4);
    const float adn = a_d[n * 8 + h];
    const int beg = offsets[n], end = offsets[n + 1];

    float pself = __expf(lrelu(a_s[n * 8 + h] + adn));
    float den = pself;
    float ax, ay, az, aw;
    {
        half4 v = *(const half4*)(xs + (long)n * HC + ch);
        ax = pself * (float)v[0]; ay = pself * (float)v[1];
        az = pself * (float)v[2]; aw = pself * (float)v[3];
    }

    for (int base = beg; base < end; base += 64) {
        const int cnt = min(64, end - base);
        int sidx = 0;
        if (lane < cnt) {
            sidx = ssrc[base + lane];
            const float4* ap = (const float4*)(a_s + (long)sidx * 8);
            float4 A0 = ap[0], A1 = ap[1];
            pl[lane * 9 + 0] = __expf(lrelu(A0.x + D0.x));
            pl[lane * 9 + 1] = __expf(lrelu(A0.y + D0.y));
            pl[lane * 9 + 2] = __expf(lrelu(A0.z + D0.z));
            pl[lane * 9 + 3] = __expf(lrelu(A0.w + D0.w));
            pl[lane * 9 + 4] = __expf(lrelu(A1.x + D1.x));
            pl[lane * 9 + 5] = __expf(lrelu(A1.y + D1.y));
            pl[lane * 9 + 6] = __expf(lrelu(A1.z + D1.z));
            pl[lane * 9 + 7] = __expf(lrelu(A1.w + D1.w));
        }
        asm volatile("s_waitcnt lgkmcnt(0)" ::: "memory");

        int u = 0;
        for (; u + 8 <= cnt; u += 8) {
            int s0 = __shfl(sidx, u + 0), s1 = __shfl(sidx, u + 1);
            int s2 = __shfl(sidx, u + 2), s3 = __shfl(sidx, u + 3);
            int s4 = __shfl(sidx, u + 4), s5 = __shfl(sidx, u + 5);
            int s6 = __shfl(sidx, u + 6), s7 = __shfl(sidx, u + 7);
            half4 v0 = *(const half4*)(xs + (long)s0 * HC + ch);
            half4 v1 = *(const half4*)(xs + (long)s1 * HC + ch);
            half4 v2 = *(const half4*)(xs + (long)s2 * HC + ch);
            half4 v3 = *(const half4*)(xs + (long)s3 * HC + ch);
            half4 v4 = *(const half4*)(xs + (long)s4 * HC + ch);
            half4 v5 = *(const half4*)(xs + (long)s5 * HC + ch);
            half4 v6 = *(const half4*)(xs + (long)s6 * HC + ch);
            half4 v7 = *(const half4*)(xs + (long)s7 * HC + ch);
            float p0 = pl[(u + 0) * 9 + h], p1 = pl[(u + 1) * 9 + h];
            float p2 = pl[(u + 2) * 9 + h], p3 = pl[(u + 3) * 9 + h];
            float p4 = pl[(u + 4) * 9 + h], p5 = pl[(u + 5) * 9 + h];
            float p6 = pl[(u + 6) * 9 + h], p7 = pl[(u + 7) * 9 + h];
            den += ((p0 + p1) + (p2 + p3)) + ((p4 + p5) + (p6 + p7));
            ax += p0 * (float)v0[0] + p1 * (float)v1[0] + p2 * (float)v2[0] + p3 * (float)v3[0]
                + p4 * (float)v4[0] + p5 * (float)v5[0] + p6 * (float)v6[0] + p7 * (float)v7[0];
            ay += p0 * (float)v0[1] + p1 * (float)v1[1] + p2 * (float)v2[1] + p3 * (float)v3[1]
                + p4 * (float)v4[1] + p5 * (float)v5[1] + p6 * (float)v6[1] + p7 * (float)v7[1];
            az += p0 * (float)v0[2] + p1 * (float)v1[2] + p2 * (float)v2[2] + p3 * (float)v3[2]
                + p4 * (float)v4[2] + p5 * (float)v5[2] + p6 * (float)v6[2] + p7 * (float)v7[2];
            aw += p0 * (float)v0[3] + p1 * (float)v1[3] + p2 * (float)v2[3] + p3 * (float)v3[3]
                + p4 * (float)v4[3] + p5 * (float)v5[3] + p6 * (float)v6[3] + p7 * (float)v7[3];
        }
        for (; u < cnt; ++u) {
            int s = __shfl(sidx, u);
            float p = pl[u * 9 + h];
            half4 v = *(const half4*)(xs + (long)s * HC + ch);
            den += p;
            ax += p * (float)v[0]; ay += p * (float)v[1];
            az += p * (float)v[2]; aw += p * (float)v[3];
        }
    }
    float inv = 1.0f / den;
    float4 b = *(const float4*)(bias + ch);
    float ox = ax * inv + b.x, oy = ay * inv + b.y;
    float oz = az * inv + b.z, ow = aw * inv + b.w;
    ox = ox > 0.f ? ox : expm1f(ox);
    oy = oy > 0.f ? oy : expm1f(oy);
    oz = oz > 0.f ? oz : expm1f(oz);
    ow = ow > 0.f ? ow : expm1f(ow);
    half4 ho;
    ho[0] = (_Float16)ox; ho[1] = (_Float16)oy;
    ho[2] = (_Float16)oz; ho[3] = (_Float16)ow;
    *(half4*)(out + (long)n * HC + ch) = ho;
}

// layer 2: H=1, C=64; scores via shfl; fp16 rows of 128B; f32 output.
__global__ __launch_bounds__(256)
void agg2(const _Float16* __restrict__ xs, const float* __restrict__ a_s,
          const float* __restrict__ a_d, const int* __restrict__ offsets,
          const int* __restrict__ ssrc, const float* __restrict__ bias,
          float* __restrict__ out) {
    const int wave = (blockIdx.x * blockDim.x + threadIdx.x) >> 6;
    const int lane = threadIdx.x & 63;
    if (wave >= NN) return;
    const int n = wave;

    const float adn = a_d[n];
    const int beg = offsets[n], end = offsets[n + 1];

    float pself = __expf(lrelu(a_s[n] + adn));
    float den = pself;
    float acc = pself * (float)xs[(long)n * OUT_CH + lane];

    for (int base = beg; base < end; base += 64) {
        const int cnt = min(64, end - base);
        int sidx = 0;
        float pe = 0.f;
        if (lane < cnt) {
            sidx = ssrc[base + lane];
            pe = __expf(lrelu(a_s[sidx] + adn));
        }
        int u = 0;
        for (; u + 8 <= cnt; u += 8) {
            int s0 = __shfl(sidx, u + 0), s1 = __shfl(sidx, u + 1);
            int s2 = __shfl(sidx, u + 2), s3 = __shfl(sidx, u + 3);
            int s4 = __shfl(sidx, u + 4), s5 = __shfl(sidx, u + 5);
            int s6 = __shfl(sidx, u + 6), s7 = __shfl(sidx, u + 7);
            float p0 = __shfl(pe, u + 0), p1 = __shfl(pe, u + 1);
            float p2 = __shfl(pe, u + 2), p3 = __shfl(pe, u + 3);
            float p4 = __shfl(pe, u + 4), p5 = __shfl(pe, u + 5);
            float p6 = __shfl(pe, u + 6), p7 = __shfl(pe, u + 7);
            float v0 = (float)xs[(long)s0 * OUT_CH + lane];
            float v1 = (float)xs[(long)s1 * OUT_CH + lane];
            float v2 = (float)xs[(long)s2 * OUT_CH + lane];
            float v3 = (float)xs[(long)s3 * OUT_CH + lane];
            float v4 = (float)xs[(long)s4 * OUT_CH + lane];
            float v5 = (float)xs[(long)s5 * OUT_CH + lane];
            float v6 = (float)xs[(long)s6 * OUT_CH + lane];
            float v7 = (float)xs[(long)s7 * OUT_CH + lane];
            den += ((p0 + p1) + (p2 + p3)) + ((p4 + p5) + (p6 + p7));
            acc += p0 * v0 + p1 * v1 + p2 * v2 + p3 * v3
                 + p4 * v4 + p5 * v5 + p6 * v6 + p7 * v7;
        }
        for (; u < cnt; ++u) {
            int s = __shfl(sidx, u);
            float p = __shfl(pe, u);
            den += p;
            acc += p * (float)xs[(long)s * OUT_CH + lane];
        }
    }
    out[(long)n * OUT_CH + lane] = acc / den + bias[lane];
}

// ---------------- launch ----------------

extern "C" void kernel_launch(void* const* d_in, const int* in_sizes, int n_in,
                              void* d_out, int out_size, void* d_ws, size_t ws_size,
                              hipStream_t stream) {
    const float* x     = (const float*)d_in[0];
    const int*   ei    = (const int*)d_in[1];      // int32 edge index [2, E]
    const float* W1    = (const float*)d_in[2];
    const float* atts1 = (const float*)d_in[3];
    const float* attd1 = (const float*)d_in[4];
    const float* bias1 = (const float*)d_in[5];
    const float* W2    = (const float*)d_in[6];
    const float* atts2 = (const float*)d_in[7];
    const float* attd2 = (const float*)d_in[8];
    const float* bias2 = (const float*)d_in[9];
    float*       out   = (float*)d_out;

    const int* srcp = ei;
    const int* dstp = ei + NE;

    char* ws = (char*)d_ws;
    size_t off = 0;
    auto alloc = [&](size_t bytes) -> void* {
        void* p = ws + off;
        off += (bytes + 255) & ~(size_t)255;
        return p;
    };
    _Float16* xh    = (_Float16*)alloc((size_t)NN * IN_CH * 2);  // 12.8 MB
    _Float16* xs1h  = (_Float16*)alloc((size_t)NN * HC * 2);     // 25.6 MB
    _Float16* h1h   = (_Float16*)alloc((size_t)NN * HC * 2);     // 25.6 MB
    _Float16* W1t   = (_Float16*)alloc((size_t)HC * IN_CH * 2);  // 64 KB
    _Float16* W2t   = (_Float16*)alloc((size_t)OUT_CH * HC * 2); // 32 KB
    float*    as1   = (float*)alloc((size_t)NN * HEADS * 4);
    float*    ad1   = (float*)alloc((size_t)NN * HEADS * 4);
    int*   deg      = (int*)alloc((size_t)NN * 4);
    int*   offsets  = (int*)alloc((size_t)(NN + 1) * 4);
    int*   cursor   = (int*)alloc((size_t)NN * 4);
    int*   ssrc     = (int*)alloc((size_t)NE * 4);
    int*   excl     = (int*)alloc((size_t)NN * 4);
    int*   bsum     = (int*)alloc((size_t)SCAN_BLOCKS * 4);
    int*   boff     = (int*)alloc((size_t)SCAN_BLOCKS * 4);
    // layer-2 scratch aliases layer-1 buffers dead after agg1:
    _Float16* xs2h = xs1h;
    float*    as2  = as1;
    float*    ad2  = ad1;

    // --- CSR build (counting sort by dst, 3-phase parallel scan) ---
    hipMemsetAsync(deg, 0, (size_t)NN * 4, stream);
    hist_kernel<<<(NE + 255) / 256, 256, 0, stream>>>(dstp, deg);
    scan_phase1<<<SCAN_BLOCKS, 256, 0, stream>>>(deg, excl, bsum);
    scan_phase2<<<1, 256, 0, stream>>>(bsum, boff, offsets);
    scan_phase3<<<SCAN_BLOCKS, 256, 0, stream>>>(excl, boff, offsets, cursor);
    scatter_kernel<<<(NE + 255) / 256, 256, 0, stream>>>(srcp, dstp, cursor, ssrc);

    // --- fp16 prep ---
    cast_f32_f16<<<(NN * IN_CH / 8 + 255) / 256, 256, 0, stream>>>(x, xh, NN * IN_CH / 8);
    transpose_cast<<<(IN_CH * HC + 255) / 256, 256, 0, stream>>>(W1, W1t, IN_CH, HC);
    transpose_cast<<<(HC * OUT_CH + 255) / 256, 256, 0, stream>>>(W2, W2t, HC, OUT_CH);

    // --- layer 1 ---
    {
        dim3 grid((NN + 63) / 64, HC / 64);
        gemm_mfma_h<<<grid, 256, 0, stream>>>(xh, W1t, xs1h, NN, HC, IN_CH);
    }
    attcoef1<<<(NN * HEADS + 255) / 256, 256, 0, stream>>>(xs1h, atts1, attd1, as1, ad1);
    agg1<<<(NN + 3) / 4, 256, 0, stream>>>(xs1h, as1, ad1, offsets, ssrc, bias1, h1h);

    // --- layer 2 ---
    {
        dim3 grid((NN + 63) / 64, OUT_CH / 64);
        gemm_mfma_h<<<grid, 256, 0, stream>>>(h1h, W2t, xs2h, NN, OUT_CH, HC);
    }
    attcoef2<<<(NN + 255) / 256, 256, 0, stream>>>(xs2h, atts2, attd2, as2, ad2);
    agg2<<<(NN + 3) / 4, 256, 0, stream>>>(xs2h, as2, ad2, offsets, ssrc, bias2, out);
}